// Round 18
// baseline (1450.523 us; speedup 1.0000x reference)
//
#include <hip/hip_runtime.h>
#include <hip/hip_bf16.h>
#include <math.h>

#define NB   32
#define KG   2048
#define NSEQ 2049
#define DIM  256
#define NH   4
#define DH   64
#define MF   266
#define FFD  1024
#define BN   (NB*NSEQ)          // 65568
#define FFROWS2 32784           // BN/2
#define NORMC 0.35355339059327376f   // 64^-0.25
#define RATIOC (1.0f/16.309506430300091f) // 266^-0.5

typedef __attribute__((ext_vector_type(8))) short short8;
typedef __attribute__((ext_vector_type(4))) float f32x4;
#define MFMA16(a,b,c) __builtin_amdgcn_mfma_f32_16x16x32_bf16(a,b,c,0,0,0)

__device__ __forceinline__ short f2b(float f){
  union{ __hip_bfloat16 h; short s;} u; u.h = __float2bfloat16(f); return u.s;
}
__device__ __forceinline__ float b2f(short s){
  union{ short s; __hip_bfloat16 h;} u; u.s = s; return __bfloat162float(u.h);
}
__device__ __forceinline__ float gelu_f(float x){
  return 0.5f*x*(1.0f+erff(x*0.70710678118654752f));
}
__device__ __forceinline__ void gload16(const short* g, short* l){
  __builtin_amdgcn_global_load_lds(
      (const __attribute__((address_space(1))) void*)g,
      (__attribute__((address_space(3))) void*)l, 16, 0, 0);
}
// bijective XCD-aware block swizzle (m204 chunked variant): consecutive
// logical flat ids land on the same XCD's contiguous chunk.
__device__ __forceinline__ void xcd_swz(int &bx, int &by){
  int nx = gridDim.x;
  int nwg = nx * gridDim.y;
  int flat = by*nx + bx;
  int q = nwg >> 3, r = nwg & 7;
  int x = flat & 7, base = flat >> 3;
  int swz = (x < r ? x*(q+1) : r*(q+1) + (x-r)*q) + base;
  bx = swz % nx; by = swz / nx;
}
__device__ __forceinline__ float waveSum(float v){
  #pragma unroll
  for(int o=32;o>0;o>>=1) v += __shfl_down(v,o);
  return v;   // lane 0 only
}
__device__ __forceinline__ float waveMax(float v){
  #pragma unroll
  for(int o=32;o>0;o>>=1) v = fmaxf(v,__shfl_down(v,o));
  return v;   // lane 0 only
}
__device__ __forceinline__ float xorSum64(float v){
  v += __shfl_xor(v,32); v += __shfl_xor(v,16); v += __shfl_xor(v,8);
  v += __shfl_xor(v,4);  v += __shfl_xor(v,2);  v += __shfl_xor(v,1);
  return v;   // exact, all lanes
}
__device__ __forceinline__ float blockSum256(float v, float* red){
  int lane = threadIdx.x & 63, wid = threadIdx.x >> 6;
  v = waveSum(v);
  __syncthreads();
  if(lane==0) red[wid]=v;
  __syncthreads();
  return red[0]+red[1]+red[2]+red[3];
}
__device__ __forceinline__ float blockMax256(float v, float* red){
  int lane = threadIdx.x & 63, wid = threadIdx.x >> 6;
  v = waveMax(v);
  __syncthreads();
  if(lane==0) red[wid]=v;
  __syncthreads();
  return fmaxf(fmaxf(red[0],red[1]),fmaxf(red[2],red[3]));
}
__device__ __forceinline__ unsigned fenc(float f){
  unsigned u = __float_as_uint(f);
  return (u & 0x80000000u) ? ~u : (u | 0x80000000u);
}
__device__ __forceinline__ float fdec(unsigned u){
  return (u & 0x80000000u) ? __uint_as_float(u & 0x7FFFFFFFu) : __uint_as_float(~u);
}

// ---------------- embed + fused LN1(layer0) -> ybf
__global__ __launch_bounds__(256) void embed_kernel(
    const float* __restrict__ expr, const float* __restrict__ coords,
    const float* __restrict__ gene_emb, const float* __restrict__ pos_emb,
    const float* __restrict__ val_w, const float* __restrict__ val_b,
    const float* __restrict__ val_g, const float* __restrict__ val_bb,
    const float* __restrict__ sp_w, const float* __restrict__ sp_b,
    const float* __restrict__ sp_g, const float* __restrict__ sp_bb,
    const float* __restrict__ ln_g, const float* __restrict__ ln_b,
    float* __restrict__ x, short* __restrict__ ybf){
  int w = threadIdx.x >> 6, l = threadIdx.x & 63;
  int row = blockIdx.x*4 + w;
  int b = row / NSEQ, n = row % NSEQ;
  int d0 = l*4;
  float4 v;
  if(n==0){
    float c0 = coords[b*2], c1 = coords[b*2+1];
    float4 w0 = *reinterpret_cast<const float4*>(sp_w + d0);
    float4 w1 = *reinterpret_cast<const float4*>(sp_w + DIM + d0);
    float4 bb = *reinterpret_cast<const float4*>(sp_b + d0);
    v = make_float4(c0*w0.x+c1*w1.x+bb.x, c0*w0.y+c1*w1.y+bb.y,
                    c0*w0.z+c1*w1.z+bb.z, c0*w0.w+c1*w1.w+bb.w);
  } else {
    float e = expr[(size_t)b*KG + (n-1)];
    float4 vw = *reinterpret_cast<const float4*>(val_w + d0);
    float4 vb = *reinterpret_cast<const float4*>(val_b + d0);
    v = make_float4(e*vw.x+vb.x, e*vw.y+vb.y, e*vw.z+vb.z, e*vw.w+vb.w);
  }
  float mu = xorSum64(v.x+v.y+v.z+v.w)*(1.0f/DIM);
  float cx=v.x-mu, cy=v.y-mu, cz=v.z-mu, cw=v.w-mu;
  float var = xorSum64(cx*cx+cy*cy+cz*cz+cw*cw)*(1.0f/DIM);
  float r = rsqrtf(var + 1e-5f);
  float4 g  = (n==0)? *reinterpret_cast<const float4*>(sp_g + d0)
                    : *reinterpret_cast<const float4*>(val_g + d0);
  float4 be = (n==0)? *reinterpret_cast<const float4*>(sp_bb + d0)
                    : *reinterpret_cast<const float4*>(val_bb + d0);
  float4 h = make_float4(gelu_f(cx*r*g.x+be.x), gelu_f(cy*r*g.y+be.y),
                         gelu_f(cz*r*g.z+be.z), gelu_f(cw*r*g.w+be.w));
  if(n!=0){
    float4 ge = *reinterpret_cast<const float4*>(gene_emb + (size_t)(n-1)*DIM + d0);
    float4 pe = *reinterpret_cast<const float4*>(pos_emb  + (size_t)(n-1)*DIM + d0);
    h.x += ge.x+pe.x; h.y += ge.y+pe.y; h.z += ge.z+pe.z; h.w += ge.w+pe.w;
  }
  *reinterpret_cast<float4*>(x + (size_t)row*DIM + d0) = h;
  float s2 = xorSum64(h.x+h.y+h.z+h.w);
  float mu2 = s2*(1.0f/DIM);
  float c2x=h.x-mu2, c2y=h.y-mu2, c2z=h.z-mu2, c2w=h.w-mu2;
  float var2 = xorSum64(c2x*c2x+c2y*c2y+c2z*c2z+c2w*c2w)*(1.0f/DIM);
  float r2 = rsqrtf(var2+1e-5f);
  const float4 gv = *reinterpret_cast<const float4*>(ln_g + d0);
  const float4 bv = *reinterpret_cast<const float4*>(ln_b + d0);
  short4 o = make_short4(f2b(c2x*r2*gv.x+bv.x), f2b(c2y*r2*gv.y+bv.y),
                         f2b(c2z*r2*gv.z+bv.z), f2b(c2w*r2*gv.w+bv.w));
  *reinterpret_cast<short4*>(ybf + (size_t)row*DIM + d0) = o;
}

// ---------------- LN -> bf16, wave-per-row, xor-exact
__global__ __launch_bounds__(256) void ln_bf4(const float* __restrict__ xin,
    const float* __restrict__ g, const float* __restrict__ bb, short* __restrict__ ybf){
  int w = threadIdx.x >> 6, l = threadIdx.x & 63;
  int row = blockIdx.x*4 + w;
  const float* xr = xin + (size_t)row*DIM;
  float4 v = *reinterpret_cast<const float4*>(xr + l*4);
  float s = xorSum64(v.x+v.y+v.z+v.w);
  float mu = s*(1.0f/DIM);
  float cx=v.x-mu, cy=v.y-mu, cz=v.z-mu, cw=v.w-mu;
  float var = xorSum64(cx*cx+cy*cy+cz*cz+cw*cw)*(1.0f/DIM);
  float r = rsqrtf(var+1e-5f);
  const float4 gv = *reinterpret_cast<const float4*>(g + l*4);
  const float4 bv = *reinterpret_cast<const float4*>(bb + l*4);
  short4 o = make_short4(f2b(cx*r*gv.x+bv.x), f2b(cy*r*gv.y+bv.y),
                         f2b(cz*r*gv.z+bv.z), f2b(cw*r*gv.w+bv.w));
  *reinterpret_cast<short4*>(ybf + (size_t)row*DIM + l*4) = o;
}

// ---------------- fused weight prep: 14 matrices, 32x32 LDS tile transpose
#define NW 14
struct WPArgs {
  const float* src[NW];
  short* dst[NW];
  int K[NW], N[NW];
  int ts[NW+1];
};
__global__ __launch_bounds__(256) void wprep_fused(WPArgs a){
  __shared__ float tile[32][33];
  int bx = blockIdx.x, t = threadIdx.x;
  int i = 0;
  while(bx >= a.ts[i+1]) i++;
  int tl = bx - a.ts[i];
  int N = a.N[i], K = a.K[i];
  int tcols = N >> 5;
  int tr = tl / tcols, tc = tl - tr*tcols;
  const float* src = a.src[i];
  short* dst = a.dst[i];
  int r = t>>3, c4 = (t&7)*4;
  float4 v = *reinterpret_cast<const float4*>(src + (size_t)(tr*32+r)*N + tc*32 + c4);
  tile[r][c4+0]=v.x; tile[r][c4+1]=v.y; tile[r][c4+2]=v.z; tile[r][c4+3]=v.w;
  __syncthreads();
  short4 o = make_short4(f2b(tile[c4+0][r]), f2b(tile[c4+1][r]),
                         f2b(tile[c4+2][r]), f2b(tile[c4+3][r]));
  *reinterpret_cast<short4*>(dst + (size_t)(tc*32+r)*K + tr*32 + c4) = o;
}

// ---------------- MFMA GEMM v4: BK=64, XOR-swizzled LDS, XCD-swizzled grid
template<int EPI, int OBF, int WBF>
__global__ __launch_bounds__(256) void mgemm2(
    const short* __restrict__ A, const short* __restrict__ Bt,
    const float* __restrict__ bias, void* __restrict__ Cv,
    int M, int N, int Kd, short* __restrict__ Yb){
  __shared__ short As[128*64];
  __shared__ short Bs[128*64];
  int t=threadIdx.x, l=t&63, w=t>>6, lr=l&15, lk=l>>4;
  int wm=w>>1, wn=w&1;
  int bx = blockIdx.x, by = blockIdx.y;
  xcd_swz(bx, by);
  int m0=by*128, n0=bx*128;
  f32x4 acc[4][4];
  #pragma unroll
  for(int i=0;i<4;i++)
    #pragma unroll
    for(int j=0;j<4;j++) acc[i][j]=f32x4{0.f,0.f,0.f,0.f};
  int rsw = (l>>3)&7;
  for(int k0=0;k0<Kd;k0+=64){
    #pragma unroll
    for(int p=0;p<4;p++){
      int chunk = p*256 + t;
      int row = chunk>>3, qc = chunk&7;
      short* lbase = &As[(size_t)(p*256 + w*64)*8];
      gload16(A + (size_t)(m0+row)*Kd + k0 + (qc^rsw)*8, lbase);
    }
    #pragma unroll
    for(int p=0;p<4;p++){
      int chunk = p*256 + t;
      int row = chunk>>3, qc = chunk&7;
      short* lbase = &Bs[(size_t)(p*256 + w*64)*8];
      gload16(Bt + (size_t)(n0+row)*Kd + k0 + (qc^rsw)*8, lbase);
    }
    __syncthreads();
    #pragma unroll
    for(int ks=0;ks<2;ks++){
      short8 af[4], bfr[4];
      #pragma unroll
      for(int i=0;i<4;i++)
        af[i] = *reinterpret_cast<const short8*>(&As[(wm*64+i*16+lr)*64 + ((ks*32+lk*8)^((lr&7)<<3))]);
      #pragma unroll
      for(int j=0;j<4;j++)
        bfr[j] = *reinterpret_cast<const short8*>(&Bs[(wn*64+j*16+lr)*64 + ((ks*32+lk*8)^((lr&7)<<3))]);
      #pragma unroll
      for(int i=0;i<4;i++)
        #pragma unroll
        for(int j=0;j<4;j++) acc[i][j] = MFMA16(af[i], bfr[j], acc[i][j]);
    }
    __syncthreads();
  }
  #pragma unroll
  for(int i=0;i<4;i++){
    int gm0 = m0 + wm*64 + i*16 + lk*4;
    #pragma unroll
    for(int j=0;j<4;j++){
      int gc = n0 + wn*64 + j*16 + lr;
      float bs = bias[gc];
      #pragma unroll
      for(int r=0;r<4;r++){
        int gm = gm0 + r;
        if(gm<M){
          float vv = acc[i][j][r] + bs;
          if(EPI==2) vv = gelu_f(vv);
          size_t idx = (size_t)gm*N + gc;
          if(OBF){
            ((short*)Cv)[idx] = f2b(vv);
          } else {
            float* C = (float*)Cv;
            if(EPI==1) vv += C[idx];
            C[idx] = vv;
            if(WBF) Yb[idx] = f2b(vv);
          }
        }
      }
    }
  }
}

// ---------------- fused QKV GEMM + diag_k epilogue (BK=64, swizzled, XCD-swizzled)
__global__ __launch_bounds__(256) void qkv_gemm(
    const short* __restrict__ A, const short* __restrict__ Bt,
    const float* __restrict__ bq, const float* __restrict__ bk, const float* __restrict__ bv,
    short* __restrict__ qd, short* __restrict__ kd, short* __restrict__ vd,
    float* __restrict__ diagk, int M){
  __shared__ short As[128*64];
  __shared__ short Bs[128*64];
  int t=threadIdx.x, l=t&63, w=t>>6, lr=l&15, lk=l>>4;
  int wm=w>>1, wn=w&1;
  int bx = blockIdx.x, by = blockIdx.y;
  xcd_swz(bx, by);
  int m0=by*128, n0=bx*128;
  f32x4 acc[4][4];
  #pragma unroll
  for(int i=0;i<4;i++)
    #pragma unroll
    for(int j=0;j<4;j++) acc[i][j]=f32x4{0.f,0.f,0.f,0.f};
  int rsw = (l>>3)&7;
  for(int k0=0;k0<DIM;k0+=64){
    #pragma unroll
    for(int p=0;p<4;p++){
      int chunk = p*256 + t;
      int row = chunk>>3, qc = chunk&7;
      short* lbase = &As[(size_t)(p*256 + w*64)*8];
      gload16(A + (size_t)(m0+row)*DIM + k0 + (qc^rsw)*8, lbase);
    }
    #pragma unroll
    for(int p=0;p<4;p++){
      int chunk = p*256 + t;
      int row = chunk>>3, qc = chunk&7;
      short* lbase = &Bs[(size_t)(p*256 + w*64)*8];
      gload16(Bt + (size_t)(n0+row)*DIM + k0 + (qc^rsw)*8, lbase);
    }
    __syncthreads();
    #pragma unroll
    for(int ks=0;ks<2;ks++){
      short8 af[4], bfr[4];
      #pragma unroll
      for(int i=0;i<4;i++)
        af[i] = *reinterpret_cast<const short8*>(&As[(wm*64+i*16+lr)*64 + ((ks*32+lk*8)^((lr&7)<<3))]);
      #pragma unroll
      for(int j=0;j<4;j++)
        bfr[j] = *reinterpret_cast<const short8*>(&Bs[(wn*64+j*16+lr)*64 + ((ks*32+lk*8)^((lr&7)<<3))]);
      #pragma unroll
      for(int i=0;i<4;i++)
        #pragma unroll
        for(int j=0;j<4;j++) acc[i][j] = MFMA16(af[i], bfr[j], acc[i][j]);
    }
    __syncthreads();
  }
  bool isK = (bx==2) || (bx==3);
  int headq = ((n0 + wn*64) - 256) >> 6;
  #pragma unroll
  for(int i=0;i<4;i++){
    int gm0 = m0 + wm*64 + i*16 + lk*4;
    float sq[4] = {0.f,0.f,0.f,0.f};
    #pragma unroll
    for(int j=0;j<4;j++){
      int gc = n0 + wn*64 + j*16 + lr;
      int sel = gc >> 8, col = gc & 255;
      short* dst = (sel==0)? qd : ((sel==1)? kd : vd);
      const float* bp = (sel==0)? bq : ((sel==1)? bk : bv);
      float bs = bp[col];
      #pragma unroll
      for(int r=0;r<4;r++){
        int gm = gm0 + r;
        if(gm<M){
          short sv = f2b(acc[i][j][r] + bs);
          dst[(size_t)gm*DIM + col] = sv;
          if(isK){ float kv = b2f(sv); sq[r] += kv*kv; }
        }
      }
    }
    if(isK){
      #pragma unroll
      for(int r=0;r<4;r++){
        float s = sq[r];
        s += __shfl_xor(s,1); s += __shfl_xor(s,2);
        s += __shfl_xor(s,4); s += __shfl_xor(s,8);
        if(lr==0){
          int gm = gm0 + r;
          if(gm<M){
            int bb_ = gm / NSEQ, nn_ = gm - bb_*NSEQ;
            diagk[((size_t)(bb_*NH+headq))*NSEQ + nn_] = 0.0625f*s;
          }
        }
      }
    }
  }
}

// ---------------- projbf + kmax init
__global__ __launch_bounds__(256) void projprep_kernel(const float* __restrict__ proj,
    short* __restrict__ projbf, unsigned* __restrict__ kmax){
  int i = blockIdx.x*256 + threadIdx.x;
  if(i==0) *kmax = 0u;
  if(i < 320*64){
    int m = i>>6, d = i&63;
    float v = (m<MF)? proj[(size_t)m*DH + d]*NORMC : 0.f;
    projbf[i] = f2b(v);
  }
}

// ---------------- kside pass0 v2: 64-key chunks, gload16 swizzled, XCD-swizzled
__global__ __launch_bounds__(256) void kside_max(
    const short* __restrict__ kbf, const short* __restrict__ projbf,
    unsigned* __restrict__ kmax){
  __shared__ short kS[64*64];
  __shared__ float red[4];
  int t=threadIdx.x, l=t&63, w=t>>6, lr=l&15, lk=l>>4;
  int split = blockIdx.x, bh = blockIdx.y;
  xcd_swz(split, bh);
  int b=bh>>2, h=bh&3;
  int c0 = split*5, c1 = min(c0+5, 33);
  int nf = (w==3)?5:4;
  short8 apf[5][2];
  #pragma unroll
  for(int fi=0;fi<5;fi++){
    int fr = (fi<4)? (fi*4+w) : 16;
    #pragma unroll
    for(int ks=0;ks<2;ks++)
      apf[fi][ks] = *reinterpret_cast<const short8*>(projbf + (fr*16+lr)*64 + ks*32 + lk*8);
  }
  int rsw = (l>>3)&7;
  float lmax = -3.0e38f;
  for(int ch=c0; ch<c1; ++ch){
    int n0 = ch*64;
    __syncthreads();
    #pragma unroll
    for(int p=0;p<2;p++){
      int chunk = p*256 + t;
      int row = chunk>>3, qc = chunk&7;
      short* lbase = &kS[(size_t)(p*256 + w*64)*8];
      gload16(kbf + (size_t)(b*NSEQ + n0 + row)*DIM + h*DH + (qc^rsw)*8, lbase);
    }
    __syncthreads();
    for(int fi=0;fi<nf;fi++){
      int fr = (fi<4)? (fi*4+w) : 16;
      #pragma unroll
      for(int fn=0;fn<4;fn++){
        f32x4 xa = f32x4{0.f,0.f,0.f,0.f};
        #pragma unroll
        for(int ks=0;ks<2;ks++){
          short8 bk = *reinterpret_cast<const short8*>(&kS[(fn*16+lr)*64 + ((ks*32+lk*8)^((lr&7)<<3))]);
          xa = MFMA16(apf[fi][ks], bk, xa);
        }
        #pragma unroll
        for(int r=0;r<4;r++){
          int m = fr*16 + lk*4 + r;
          int n = n0 + fn*16 + lr;
          if(m<MF && n<NSEQ) lmax = fmaxf(lmax, xa[r]);
        }
      }
    }
  }
  float bm = blockMax256(lmax, red);
  if(t==0) atomicMax(kmax, fenc(bm));
}

// ---------------- kside pass1 v6: conflict-free LDS (stride-64 + chunk XOR), XCD-swizzled
__global__ __launch_bounds__(256) void kside_ctx(
    const short* __restrict__ kbf, const short* __restrict__ vbf,
    const short* __restrict__ projbf, const float* __restrict__ diagk,
    const unsigned* __restrict__ kmax, float* __restrict__ ctxP){
  __shared__ short kS[64*64];     // swizzled via gload source
  __shared__ short vT[64*64];     // [d][n], chunk-XOR swizzled
  __shared__ short kfS[80*64];    // [m'][n], chunk-XOR swizzled
  __shared__ float diagS[64];
  int t=threadIdx.x, l=t&63, w=t>>6, lr=l&15, lk=l>>4;
  int bxx = blockIdx.x, byy = blockIdx.y;
  xcd_swz(bxx, byy);
  int fb=bxx&3, qh=bxx>>2, bh=byy; int b=bh>>2, h=bh&3;
  int F0 = fb*5;
  int ch0 = qh*17, ch1 = min(33, ch0+17);
  float stab = fdec(*kmax);
  short8 apf0[2], apf1[2];
  #pragma unroll
  for(int ks=0;ks<2;ks++){
    apf0[ks] = *reinterpret_cast<const short8*>(projbf + ((F0+w)*16+lr)*64 + ks*32 + lk*8);
    apf1[ks] = *reinterpret_cast<const short8*>(projbf + ((F0+4)*16+lr)*64 + ks*32 + lk*8);
  }
  f32x4 ctx[5];
  #pragma unroll
  for(int f=0;f<5;f++) ctx[f]=f32x4{0.f,0.f,0.f,0.f};
  f32x4 ksc0 = f32x4{0.f,0.f,0.f,0.f};
  f32x4 ksc1 = f32x4{0.f,0.f,0.f,0.f};
  const short ONE=(short)0x3F80;
  const short8 ones8 = {ONE,ONE,ONE,ONE,ONE,ONE,ONE,ONE};
  int rsw = (l>>3)&7;
  for(int ch=ch0; ch<ch1; ++ch){
    int n0 = ch*64;
    __syncthreads();
    // stage k (64x64) via gload16, source-swizzled
    #pragma unroll
    for(int p=0;p<2;p++){
      int chunk = p*256 + t;
      int row = chunk>>3, qc = chunk&7;
      short* lbase = &kS[(size_t)(p*256 + w*64)*8];
      gload16(kbf + (size_t)(b*NSEQ + n0 + row)*DIM + h*DH + (qc^rsw)*8, lbase);
    }
    // stage v transposed vT[d][n], chunk-XOR: phys chunk = p ^ (d&7)
    #pragma unroll
    for(int p=0;p<8;p++){
      int n2 = 2*w + 8*p;       // data chunk = p, offset 2w
      int dd = l;
      int gn0=n0+n2, gn1=gn0+1;
      short v0 = (gn0<NSEQ)? vbf[((size_t)(b*NSEQ+gn0))*DIM + h*DH + dd] : (short)0;
      short v1 = (gn1<NSEQ)? vbf[((size_t)(b*NSEQ+gn1))*DIM + h*DH + dd] : (short)0;
      *reinterpret_cast<short2*>(&vT[dd*64 + (p^(dd&7))*8 + 2*w]) = make_short2(v0,v1);
    }
    if(t<64) diagS[t] = (n0+t<NSEQ)? diagk[(size_t)bh*NSEQ + n0+t] : 0.f;
    __syncthreads();
    // xd -> kf for group fl=w
    #pragma unroll
    for(int fn=0;fn<4;fn++){
      f32x4 xa = f32x4{0.f,0.f,0.f,0.f};
      #pragma unroll
      for(int ks=0;ks<2;ks++){
        short8 bk = *reinterpret_cast<const short8*>(&kS[(fn*16+lr)*64 + ((ks*32+lk*8)^((lr&7)<<3))]);
        xa = MFMA16(apf0[ks], bk, xa);
      }
      float dgn = diagS[fn*16+lr];
      #pragma unroll
      for(int r=0;r<4;r++){
        int m = (F0+w)*16 + lk*4 + r;
        int n = n0 + fn*16 + lr;
        float kf = (m<MF && n<NSEQ)? RATIOC*(__expf(xa[r]-dgn-stab)+1e-4f) : 0.f;
        int rowm = w*16 + lk*4 + r;
        int dc = fn*2 + (lr>>3);
        kfS[rowm*64 + ((dc^((lk*4+r)&7))<<3) + (lr&7)] = f2b(kf);
      }
    }
    if(w==0){
      #pragma unroll
      for(int fn=0;fn<4;fn++){
        f32x4 xa = f32x4{0.f,0.f,0.f,0.f};
        #pragma unroll
        for(int ks=0;ks<2;ks++){
          short8 bk = *reinterpret_cast<const short8*>(&kS[(fn*16+lr)*64 + ((ks*32+lk*8)^((lr&7)<<3))]);
          xa = MFMA16(apf1[ks], bk, xa);
        }
        float dgn = diagS[fn*16+lr];
        #pragma unroll
        for(int r=0;r<4;r++){
          int m = (F0+4)*16 + lk*4 + r;
          int n = n0 + fn*16 + lr;
          float kf = (m<MF && n<NSEQ)? RATIOC*(__expf(xa[r]-dgn-stab)+1e-4f) : 0.f;
          int rowm = 64 + lk*4 + r;
          int dc = fn*2 + (lr>>3);
          kfS[rowm*64 + ((dc^((lk*4+r)&7))<<3) + (lr&7)] = f2b(kf);
        }
      }
    }
    __syncthreads();
    // ksum + ctx: contraction over 64 keys = 2 K-steps (chunk-XOR reads)
    #pragma unroll
    for(int ks2=0;ks2<2;ks2++){
      int pc = ((ks2*4+lk)^(lr&7))<<3;
      short8 bv = *reinterpret_cast<const short8*>(&vT[(w*16+lr)*64 + pc]);
      short8 a0 = *reinterpret_cast<const short8*>(&kfS[(w*16+lr)*64 + pc]);
      short8 a4 = *reinterpret_cast<const short8*>(&kfS[(64+lr)*64 + pc]);
      ksc0 = MFMA16(a0, ones8, ksc0);
      ksc1 = MFMA16(a4, ones8, ksc1);
      #pragma unroll
      for(int fl=0;fl<5;fl++){
        short8 a_ = *reinterpret_cast<const short8*>(&kfS[(fl*16+lr)*64 + pc]);
        ctx[fl] = MFMA16(a_, bv, ctx[fl]);
      }
    }
  }
  float* P = ctxP + ((size_t)(qh*128 + bh))*65*320;
  #pragma unroll
  for(int fl=0;fl<5;fl++){
    #pragma unroll
    for(int r=0;r<4;r++){
      int m = (F0+fl)*16 + lk*4 + r;
      P[(size_t)(w*16+lr)*320 + m] = ctx[fl][r];
    }
  }
  if(lr==0){
    #pragma unroll
    for(int r=0;r<4;r++){
      int m = (F0+w)*16 + lk*4 + r;
      P[(size_t)64*320 + m] = ksc0[r];
    }
    if(w==0){
      #pragma unroll
      for(int r=0;r<4;r++){
        int m = (F0+4)*16 + lk*4 + r;
        P[(size_t)64*320 + m] = ksc1[r];
      }
    }
  }
}

// ---------------- reduce 2 fp32 partials -> bf16 ctxT[bh][80][288]
__global__ __launch_bounds__(256) void ctx_reduce(const float* __restrict__ ctxP, short* __restrict__ ctxT){
  int row = blockIdx.x, bh = blockIdx.y, t = threadIdx.x;
  short* o = ctxT + ((size_t)bh*80 + row)*288;
  if(row < 65){
    const float* P0 = ctxP + ((size_t)bh*65 + row)*320;
    const float* P1 = ctxP + ((size_t)(128+bh)*65 + row)*320;
    for(int m=t; m<288; m+=256)
      o[m] = (m<272)? f2b(P0[m]+P1[m]) : (short)0;
  } else {
    for(int m=t; m<288; m+=256) o[m] = 0;
  }
}

// ---------------- qside (staged pipeline, qS aliased into qfS), XCD-swizzled
__global__ __launch_bounds__(256) void qside_mfma(
    const short* __restrict__ qbf, const short* __restrict__ projbf,
    const short* __restrict__ ctxT, short* __restrict__ obf){
  __shared__ short qfS[64*296];
  __shared__ float diagS[64];
  short* qS = qfS;
  int t=threadIdx.x, l=t&63, w=t>>6, lr=l&15, lk=l>>4;
  int bxx = blockIdx.x, byy = blockIdx.y;
  xcd_swz(bxx, byy);
  int n0 = bxx*64, bh = byy;
  int b = bh>>2, h = bh&3;
  const short8 z8 = {0,0,0,0,0,0,0,0};
  {
    int r = t>>2, c8 = (t&3)*16;
    int gn = n0 + r;
    float ssq = 0.f;
    #pragma unroll
    for(int i=0;i<2;i++){
      short8 v8 = z8;
      if(gn<NSEQ) v8 = *reinterpret_cast<const short8*>(qbf + ((size_t)(b*NSEQ+gn))*DIM + h*DH + c8 + i*8);
      #pragma unroll
      for(int u=0;u<8;u++){ float fv=b2f(v8[u]); ssq += fv*fv; }
      *reinterpret_cast<short8*>(&qS[r*72+c8+i*8]) = v8;
    }
    ssq += __shfl_xor(ssq,1); ssq += __shfl_xor(ssq,2);
    if((t&3)==0) diagS[r] = 0.0625f*ssq;
  }
  short8 aq[2];
  #pragma unroll
  for(int ks=0;ks<2;ks++) aq[ks] = *reinterpret_cast<const short8*>(&qS[(w*16+lr)*72 + ks*32 + lk*8]);
  float dg[4];
  #pragma unroll
  for(int r=0;r<4;r++) dg[r] = diagS[w*16 + lk*4 + r];
  __syncthreads();
  {
    int pr = w*16 + (l>>2), pc = 272 + (l&3)*4;
    #pragma unroll
    for(int i=0;i<4;i++) qfS[pr*296 + pc + i] = 0;
  }
  f32x4 acc[17];
  #pragma unroll
  for(int f=0;f<17;f++) acc[f]=f32x4{0.f,0.f,0.f,0.f};
  #pragma unroll
  for(int f=0;f<17;f++){
    #pragma unroll
    for(int ks=0;ks<2;ks++){
      short8 bp = *reinterpret_cast<const short8*>(projbf + (f*16+lr)*64 + ks*32 + lk*8);
      acc[f] = MFMA16(aq[ks], bp, acc[f]);
    }
  }
  float rmax[4];
  #pragma unroll
  for(int r=0;r<4;r++){
    float m = -3.0e38f;
    #pragma unroll
    for(int f=0;f<17;f++){
      float v = (f==16 && lr>=10)? -3.0e38f : acc[f][r];
      m = fmaxf(m,v);
    }
    m = fmaxf(m,__shfl_xor(m,1)); m = fmaxf(m,__shfl_xor(m,2));
    m = fmaxf(m,__shfl_xor(m,4)); m = fmaxf(m,__shfl_xor(m,8));
    rmax[r]=m;
  }
  #pragma unroll
  for(int f=0;f<17;f++)
    #pragma unroll
    for(int r=0;r<4;r++){
      float qv = RATIOC*(__expf(acc[f][r] - dg[r] - rmax[r]) + 1e-4f);
      qfS[(w*16+lk*4+r)*296 + f*16 + lr] = f2b(qv);
    }
  f32x4 pv[5];
  #pragma unroll
  for(int f=0;f<5;f++) pv[f]=f32x4{0.f,0.f,0.f,0.f};
  const short* cT = ctxT + (size_t)bh*80*288;
  for(int ks=0;ks<9;ks++){
    short8 a_ = *reinterpret_cast<const short8*>(&qfS[(w*16+lr)*296 + ks*32 + lk*8]);
    #pragma unroll
    for(int f=0;f<5;f++){
      short8 bb = *reinterpret_cast<const short8*>(cT + (f*16+lr)*288 + ks*32 + lk*8);
      pv[f] = MFMA16(a_, bb, pv[f]);
    }
  }
  #pragma unroll
  for(int r=0;r<4;r++){
    int gn = n0 + w*16 + lk*4 + r;
    if(gn>=NSEQ) continue;
    float den = __shfl(pv[4][r], (l & 48), 64);
    float inv = 1.0f/den;
    size_t obase = ((size_t)(b*NSEQ+gn))*DIM + h*DH;
    #pragma unroll
    for(int f=0;f<4;f++) obf[obase + f*16 + lr] = f2b(pv[f][r]*inv);
  }
}

// ---------------- small row projection (fp32)
__global__ __launch_bounds__(256) void rowproj_kernel(const float* __restrict__ src,
    const float* __restrict__ W, const float* __restrict__ bias,
    float* __restrict__ dst, int rowstride){
  __shared__ float rs[DIM];
  int b=blockIdx.x, t=threadIdx.x;
  rs[t]=src[(size_t)b*rowstride+t];
  __syncthreads();
  float s=bias[t];
  for(int j=0;j<DIM;j++) s += rs[j]*W[(size_t)j*DIM+t];
  dst[(size_t)b*DIM+t]=s;
}

// ---------------- final pooling: pass 1 — raw scores (grid 8 x NB)
__global__ __launch_bounds__(256) void pool_scores(const float* __restrict__ qfin,
    const short* __restrict__ kk, float* __restrict__ scb){
  __shared__ float qsh[DIM];
  int kc=blockIdx.x, b=blockIdx.y, t=threadIdx.x;
  qsh[t]=qfin[b*DIM+t];
  __syncthreads();
  int kidx = kc*256 + t;
  const short* kr = kk + ((size_t)(b*NSEQ+1+kidx))*DIM;
  float s=0;
  for(int j8=0;j8<32;j8++){
    short8 kv = *reinterpret_cast<const short8*>(kr + j8*8);
    #pragma unroll
    for(int u=0;u<8;u++) s += qsh[j8*8+u]*b2f(kv[u]);
  }
  scb[(size_t)b*KG + kidx] = s*0.0625f;
}

// ---------------- pool pass 2: per-b gmax/gsum
__global__ __launch_bounds__(256) void pool_sm(const float* __restrict__ scb,
    float* __restrict__ gms){
  __shared__ float red[4];
  int b=blockIdx.x, t=threadIdx.x;
  float ls[8]; float lmax=-3.4e38f;
  #pragma unroll
  for(int i=0;i<8;i++){
    ls[i] = scb[(size_t)b*KG + t + i*256];
    lmax = fmaxf(lmax, ls[i]);
  }
  float gmax=blockMax256(lmax,red);
  float lsum=0;
  #pragma unroll
  for(int i=0;i<8;i++) lsum += __expf(ls[i]-gmax);
  float gsum=blockSum256(lsum,red);
  if(t==0){ gms[b*2]=gmax; gms[b*2+1]=gsum; }
}

// ---------------- pool pass 3: partial PV (grid 8 x NB)
__global__ __launch_bounds__(256) void pool_pv2(const float* __restrict__ scb,
    const float* __restrict__ gms, const short* __restrict__ vv,
    float* __restrict__ part){
  __shared__ float es[256];
  int kc=blockIdx.x, b=blockIdx.y, t=threadIdx.x;
  float gmax = gms[b*2];
  es[t] = __expf(scb[(size_t)b*KG + kc*256 + t] - gmax);
  __syncthreads();
  float p=0;
  for(int i=0;i<256;i++){
    int kidx = kc*256 + i;
    p += es[i] * b2f(vv[((size_t)(b*NSEQ+1+kidx))*DIM + t]);
  }
  part[((size_t)(b*8)+kc)*DIM + t] = p;
}

// ---------------- pool pass 4: finish (grid NB)
__global__ __launch_bounds__(256) void pool_fin(const float* __restrict__ part,
    const float* __restrict__ gms, float* __restrict__ pooled){
  int b=blockIdx.x, t=threadIdx.x;
  float inv = 1.0f/gms[b*2+1];
  float s=0;
  #pragma unroll
  for(int kc=0;kc<8;kc++) s += part[((size_t)(b*8)+kc)*DIM + t];
  pooled[b*DIM+t] = s*inv;
}

extern "C" void kernel_launch(void* const* d_in, const int* in_sizes, int n_in,
                              void* d_out, int out_size, void* d_ws, size_t ws_size,
                              hipStream_t stream){
  const float* expr   =(const float*)d_in[0];
  const float* coords =(const float*)d_in[1];
  const float* gene_emb=(const float*)d_in[2];
  const float* pos_emb=(const float*)d_in[3];
  const float* val_w  =(const float*)d_in[4];
  const float* val_b  =(const float*)d_in[5];
  const float* val_g  =(const float*)d_in[6];
  const float* val_bb =(const float*)d_in[7];
  const float* sp_w   =(const float*)d_in[8];
  const float* sp_b   =(const float*)d_in[9];
  const float* sp_g   =(const float*)d_in[10];
  const float* sp_bb  =(const float*)d_in[11];
  const float* p_ln1_g=(const float*)d_in[12];
  const float* p_ln1_b=(const float*)d_in[13];
  const float* p_wq   =(const float*)d_in[14];
  const float* p_bq   =(const float*)d_in[15];
  const float* p_wk   =(const float*)d_in[16];
  const float* p_bk   =(const float*)d_in[17];
  const float* p_wv   =(const float*)d_in[18];
  const float* p_bv   =(const float*)d_in[19];
  const float* p_wo   =(const float*)d_in[20];
  const float* p_bo   =(const float*)d_in[21];
  const float* p_ln2_g=(const float*)d_in[22];
  const float* p_ln2_b=(const float*)d_in[23];
  const float* p_ff1_w=(const float*)d_in[24];
  const float* p_ff1_b=(const float*)d_in[25];
  const float* p_ff2_w=(const float*)d_in[26];
  const float* p_ff2_b=(const float*)d_in[27];
  const float* proj   =(const float*)d_in[28];
  const float* q_w    =(const float*)d_in[29];
  const float* q_b    =(const float*)d_in[30];
  const float* k_w    =(const float*)d_in[31];
  const float* k_b    =(const float*)d_in[32];
  const float* v_w    =(const float*)d_in[33];
  const float* v_b    =(const float*)d_in[34];
  const float* o_w    =(const float*)d_in[35];
  const float* o_b    =(const float*)d_in[36];
  float* out = (float*)d_out;

  const size_t BND = (size_t)BN*DIM;     // 16,785,408
  size_t needB = BND*4 + BND*2*4
               + ((size_t)NB*NH*NSEQ + 4 + 2*(size_t)NB*DIM)*4
               + ((size_t)20480 + 2949120 + 1703936)*2;
  if(ws_size < needB){
    hipMemsetAsync(d_out, 0, (size_t)out_size*sizeof(float), stream);
    return;
  }
  float* ws = (float*)d_ws;
  float* x  = ws;                                  // BND fp32
  short* ybf = (short*)(x + BND);
  short* qbf = ybf + BND;
  short* kbf = qbf + BND;
  short* vbf = kbf + BND;
  float* diagk = (float*)(vbf + BND);
  unsigned* kmax = (unsigned*)(diagk + (size_t)NB*NH*NSEQ);
  float* qfin   = (float*)(kmax+4);
  float* pooled = qfin + NB*DIM;
  short* projbf = (short*)(pooled + NB*DIM);       // 320*64
  short* ctxT   = projbf + 20480;                  // 128*80*288
  short* wt     = ctxT + (size_t)128*80*288;       // 1,703,936
  const size_t LW = 786432;
  float* ctxP = (float*)ybf;   // fp32 partials in dead ybf region
  float* scb  = diagk;         // pool scores scratch (65536 floats)
  float* gms  = diagk + 65536; // 64 floats
  float* ppart= gms + 64;      // 65536 floats

  // ---- fused weight prep
  {
    WPArgs a;
    short* wtkk = wt + 2*LW;
    short* wtvv = wtkk + 65536;
    const float* s10[10] = {p_wq, p_wk, p_wv, p_wo,
                            p_wq+(size_t)DIM*DIM, p_wk+(size_t)DIM*DIM,
                            p_wv+(size_t)DIM*DIM, p_wo+(size_t)DIM*DIM,
                            k_w, v_w};
    short* d10[10] = {wt, wt+65536, wt+131072, wt+196608,
                      wt+LW, wt+LW+65536, wt+LW+131072, wt+LW+196608,
                      wtkk, wtvv};
    int ti = 0;
    for(int i=0;i<10;i++){
      a.src[i]=s10[i]; a.dst[i]=d10[i]; a.K[i]=DIM; a.N[i]=DIM;
      a.ts[i]=ti; ti+=64;
    }
    const float* sff[4] = {p_ff1_w, p_ff2_w, p_ff1_w+(size_t)DIM*FFD, p_ff2_w+(size_t)FFD*DIM};
    short* dff[4] = {wt+262144, wt+524288, wt+LW+262144, wt+LW+524288};
    int Kff[4] = {DIM, FFD, DIM, FFD};
    int Nff[4] = {FFD, DIM, FFD, DIM};
    for(int i=0;i<4;i++){
      a.src[10+i]=sff[i]; a.dst[10+i]=dff[i]; a.K[10+i]=Kff[i]; a.N[10+i]=Nff[i];
      a.ts[10+i]=ti; ti+=256;
    }
    a.ts[14]=ti;
    wprep_fused<<<1664,256,0,stream>>>(a);
  }

  // embed + fused LN1(layer 0) -> ybf
  embed_kernel<<<BN/4,256,0,stream>>>(expr,coords,gene_emb,pos_emb,val_w,val_b,val_g,val_bb,
                                      sp_w,sp_b,sp_g,sp_bb, p_ln1_g, p_ln1_b, x, ybf);

  dim3 gdd(2, (BN+127)/128);
  dim3 gqkv(6, (BN+127)/128);
  dim3 gff1(8, (FFROWS2+127)/128);
  dim3 gff2(2, (FFROWS2+127)/128);
  dim3 gkm(7, NB*NH);
  dim3 gkc(8, NB*NH);
  dim3 gcr(80, NB*NH);
  dim3 gq((NSEQ+63)/64, NB*NH);
  dim3 gps(8, NB);
  short* wtkk = wt + 2*LW;
  short* wtvv = wtkk + 65536;

  for(int l=0;l<2;l++){
    short* wl = wt + (size_t)l*LW;
    if(l>0) ln_bf4<<<BN/4,256,0,stream>>>(x, p_ln1_g+l*DIM, p_ln1_b+l*DIM, ybf);
    qkv_gemm<<<gqkv,256,0,stream>>>(ybf, wl, p_bq+l*DIM, p_bk+l*DIM, p_bv+l*DIM,
                                    qbf, kbf, vbf, diagk, BN);
    projprep_kernel<<<80,256,0,stream>>>(proj + (size_t)l*MF*DH, projbf, kmax);
    kside_max<<<gkm,256,0,stream>>>(kbf, projbf, kmax);
    kside_ctx<<<gkc,256,0,stream>>>(kbf, vbf, projbf, diagk, kmax, ctxP);
    ctx_reduce<<<gcr,256,0,stream>>>(ctxP, ctxT);
    qside_mfma<<<gq,256,0,stream>>>(qbf, projbf, ctxT, kbf);   // o -> kbf
    mgemm2<1,0,0><<<gdd,256,0,stream>>>(kbf, wl+196608, p_bo+l*DIM, x, BN, DIM, DIM, nullptr);
    ln_bf4<<<BN/4,256,0,stream>>>(x, p_ln2_g+l*DIM, p_ln2_b+l*DIM, ybf);
    // FF 2-chunk: each chunk's intermediate = FFROWS2 x FFD = qbf+kbf exactly
    for(int c2=0;c2<2;c2++){
      size_t roff=(size_t)c2*FFROWS2;
      mgemm2<2,1,0><<<gff1,256,0,stream>>>(ybf+roff*DIM, wl+262144, p_ff1_b+l*FFD, qbf,
                                           FFROWS2, FFD, DIM, nullptr);
      if(l==1)
        mgemm2<1,0,1><<<gff2,256,0,stream>>>(qbf, wl+524288, p_ff2_b+l*DIM, x+roff*DIM,
                                             FFROWS2, DIM, FFD, ybf+roff*DIM);
      else
        mgemm2<1,0,0><<<gff2,256,0,stream>>>(qbf, wl+524288, p_ff2_b+l*DIM, x+roff*DIM,
                                             FFROWS2, DIM, FFD, nullptr);
    }
  }

  // final pooling attention (ybf already holds bf16(x) via WBF epilogue)
  mgemm2<0,1,0><<<gdd,256,0,stream>>>(ybf, wtkk, k_b, kbf, BN, DIM, DIM, nullptr);
  mgemm2<0,1,0><<<gdd,256,0,stream>>>(ybf, wtvv, v_b, vbf, BN, DIM, DIM, nullptr);
  rowproj_kernel<<<NB,256,0,stream>>>(x, q_w, q_b, qfin, NSEQ*DIM);
  pool_scores<<<gps,256,0,stream>>>(qfin, kbf, scb);
  pool_sm<<<NB,256,0,stream>>>(scb, gms);
  pool_pv2<<<gps,256,0,stream>>>(scb, gms, vbf, ppart);
  pool_fin<<<NB,256,0,stream>>>(ppart, gms, pooled);
  rowproj_kernel<<<NB,256,0,stream>>>(pooled, o_w, o_b, out, DIM);
}

// Round 19
// 1345.728 us; speedup vs baseline: 1.0779x; 1.0779x over previous
//
#include <hip/hip_runtime.h>
#include <hip/hip_bf16.h>
#include <math.h>

#define NB   32
#define KG   2048
#define NSEQ 2049
#define DIM  256
#define NH   4
#define DH   64
#define MF   266
#define FFD  1024
#define BN   (NB*NSEQ)          // 65568
#define FFROWS2 32784           // BN/2
#define NORMC 0.35355339059327376f   // 64^-0.25
#define RATIOC (1.0f/16.309506430300091f) // 266^-0.5

typedef __attribute__((ext_vector_type(8))) short short8;
typedef __attribute__((ext_vector_type(4))) float f32x4;
#define MFMA16(a,b,c) __builtin_amdgcn_mfma_f32_16x16x32_bf16(a,b,c,0,0,0)

__device__ __forceinline__ short f2b(float f){
  union{ __hip_bfloat16 h; short s;} u; u.h = __float2bfloat16(f); return u.s;
}
__device__ __forceinline__ float b2f(short s){
  union{ short s; __hip_bfloat16 h;} u; u.s = s; return __bfloat162float(u.h);
}
__device__ __forceinline__ float gelu_f(float x){
  return 0.5f*x*(1.0f+erff(x*0.70710678118654752f));
}
__device__ __forceinline__ void gload16(const short* g, short* l){
  __builtin_amdgcn_global_load_lds(
      (const __attribute__((address_space(1))) void*)g,
      (__attribute__((address_space(3))) void*)l, 16, 0, 0);
}
// bijective XCD-aware block swizzle (m204 chunked variant)
__device__ __forceinline__ void xcd_swz(int &bx, int &by){
  int nx = gridDim.x;
  int nwg = nx * gridDim.y;
  int flat = by*nx + bx;
  int q = nwg >> 3, r = nwg & 7;
  int x = flat & 7, base = flat >> 3;
  int swz = (x < r ? x*(q+1) : r*(q+1) + (x-r)*q) + base;
  bx = swz % nx; by = swz / nx;
}
__device__ __forceinline__ float waveSum(float v){
  #pragma unroll
  for(int o=32;o>0;o>>=1) v += __shfl_down(v,o);
  return v;   // lane 0 only
}
__device__ __forceinline__ float waveMax(float v){
  #pragma unroll
  for(int o=32;o>0;o>>=1) v = fmaxf(v,__shfl_down(v,o));
  return v;   // lane 0 only
}
__device__ __forceinline__ float xorSum64(float v){
  v += __shfl_xor(v,32); v += __shfl_xor(v,16); v += __shfl_xor(v,8);
  v += __shfl_xor(v,4);  v += __shfl_xor(v,2);  v += __shfl_xor(v,1);
  return v;   // exact, all lanes
}
__device__ __forceinline__ float blockSum256(float v, float* red){
  int lane = threadIdx.x & 63, wid = threadIdx.x >> 6;
  v = waveSum(v);
  __syncthreads();
  if(lane==0) red[wid]=v;
  __syncthreads();
  return red[0]+red[1]+red[2]+red[3];
}
__device__ __forceinline__ float blockMax256(float v, float* red){
  int lane = threadIdx.x & 63, wid = threadIdx.x >> 6;
  v = waveMax(v);
  __syncthreads();
  if(lane==0) red[wid]=v;
  __syncthreads();
  return fmaxf(fmaxf(red[0],red[1]),fmaxf(red[2],red[3]));
}
__device__ __forceinline__ unsigned fenc(float f){
  unsigned u = __float_as_uint(f);
  return (u & 0x80000000u) ? ~u : (u | 0x80000000u);
}
__device__ __forceinline__ float fdec(unsigned u){
  return (u & 0x80000000u) ? __uint_as_float(u & 0x7FFFFFFFu) : __uint_as_float(~u);
}

// ---------------- embed + fused LN1(layer0) -> ybf
__global__ __launch_bounds__(256) void embed_kernel(
    const float* __restrict__ expr, const float* __restrict__ coords,
    const float* __restrict__ gene_emb, const float* __restrict__ pos_emb,
    const float* __restrict__ val_w, const float* __restrict__ val_b,
    const float* __restrict__ val_g, const float* __restrict__ val_bb,
    const float* __restrict__ sp_w, const float* __restrict__ sp_b,
    const float* __restrict__ sp_g, const float* __restrict__ sp_bb,
    const float* __restrict__ ln_g, const float* __restrict__ ln_b,
    float* __restrict__ x, short* __restrict__ ybf){
  int w = threadIdx.x >> 6, l = threadIdx.x & 63;
  int row = blockIdx.x*4 + w;
  int b = row / NSEQ, n = row % NSEQ;
  int d0 = l*4;
  float4 v;
  if(n==0){
    float c0 = coords[b*2], c1 = coords[b*2+1];
    float4 w0 = *reinterpret_cast<const float4*>(sp_w + d0);
    float4 w1 = *reinterpret_cast<const float4*>(sp_w + DIM + d0);
    float4 bb = *reinterpret_cast<const float4*>(sp_b + d0);
    v = make_float4(c0*w0.x+c1*w1.x+bb.x, c0*w0.y+c1*w1.y+bb.y,
                    c0*w0.z+c1*w1.z+bb.z, c0*w0.w+c1*w1.w+bb.w);
  } else {
    float e = expr[(size_t)b*KG + (n-1)];
    float4 vw = *reinterpret_cast<const float4*>(val_w + d0);
    float4 vb = *reinterpret_cast<const float4*>(val_b + d0);
    v = make_float4(e*vw.x+vb.x, e*vw.y+vb.y, e*vw.z+vb.z, e*vw.w+vb.w);
  }
  float mu = xorSum64(v.x+v.y+v.z+v.w)*(1.0f/DIM);
  float cx=v.x-mu, cy=v.y-mu, cz=v.z-mu, cw=v.w-mu;
  float var = xorSum64(cx*cx+cy*cy+cz*cz+cw*cw)*(1.0f/DIM);
  float r = rsqrtf(var + 1e-5f);
  float4 g  = (n==0)? *reinterpret_cast<const float4*>(sp_g + d0)
                    : *reinterpret_cast<const float4*>(val_g + d0);
  float4 be = (n==0)? *reinterpret_cast<const float4*>(sp_bb + d0)
                    : *reinterpret_cast<const float4*>(val_bb + d0);
  float4 h = make_float4(gelu_f(cx*r*g.x+be.x), gelu_f(cy*r*g.y+be.y),
                         gelu_f(cz*r*g.z+be.z), gelu_f(cw*r*g.w+be.w));
  if(n!=0){
    float4 ge = *reinterpret_cast<const float4*>(gene_emb + (size_t)(n-1)*DIM + d0);
    float4 pe = *reinterpret_cast<const float4*>(pos_emb  + (size_t)(n-1)*DIM + d0);
    h.x += ge.x+pe.x; h.y += ge.y+pe.y; h.z += ge.z+pe.z; h.w += ge.w+pe.w;
  }
  *reinterpret_cast<float4*>(x + (size_t)row*DIM + d0) = h;
  float s2 = xorSum64(h.x+h.y+h.z+h.w);
  float mu2 = s2*(1.0f/DIM);
  float c2x=h.x-mu2, c2y=h.y-mu2, c2z=h.z-mu2, c2w=h.w-mu2;
  float var2 = xorSum64(c2x*c2x+c2y*c2y+c2z*c2z+c2w*c2w)*(1.0f/DIM);
  float r2 = rsqrtf(var2+1e-5f);
  const float4 gv = *reinterpret_cast<const float4*>(ln_g + d0);
  const float4 bv = *reinterpret_cast<const float4*>(ln_b + d0);
  short4 o = make_short4(f2b(c2x*r2*gv.x+bv.x), f2b(c2y*r2*gv.y+bv.y),
                         f2b(c2z*r2*gv.z+bv.z), f2b(c2w*r2*gv.w+bv.w));
  *reinterpret_cast<short4*>(ybf + (size_t)row*DIM + d0) = o;
}

// ---------------- LN -> bf16, wave-per-row, xor-exact
__global__ __launch_bounds__(256) void ln_bf4(const float* __restrict__ xin,
    const float* __restrict__ g, const float* __restrict__ bb, short* __restrict__ ybf){
  int w = threadIdx.x >> 6, l = threadIdx.x & 63;
  int row = blockIdx.x*4 + w;
  const float* xr = xin + (size_t)row*DIM;
  float4 v = *reinterpret_cast<const float4*>(xr + l*4);
  float s = xorSum64(v.x+v.y+v.z+v.w);
  float mu = s*(1.0f/DIM);
  float cx=v.x-mu, cy=v.y-mu, cz=v.z-mu, cw=v.w-mu;
  float var = xorSum64(cx*cx+cy*cy+cz*cz+cw*cw)*(1.0f/DIM);
  float r = rsqrtf(var+1e-5f);
  const float4 gv = *reinterpret_cast<const float4*>(g + l*4);
  const float4 bv = *reinterpret_cast<const float4*>(bb + l*4);
  short4 o = make_short4(f2b(cx*r*gv.x+bv.x), f2b(cy*r*gv.y+bv.y),
                         f2b(cz*r*gv.z+bv.z), f2b(cw*r*gv.w+bv.w));
  *reinterpret_cast<short4*>(ybf + (size_t)row*DIM + l*4) = o;
}

// ---------------- fused weight prep: 14 matrices, 32x32 LDS tile transpose
#define NW 14
struct WPArgs {
  const float* src[NW];
  short* dst[NW];
  int K[NW], N[NW];
  int ts[NW+1];
};
__global__ __launch_bounds__(256) void wprep_fused(WPArgs a){
  __shared__ float tile[32][33];
  int bx = blockIdx.x, t = threadIdx.x;
  int i = 0;
  while(bx >= a.ts[i+1]) i++;
  int tl = bx - a.ts[i];
  int N = a.N[i], K = a.K[i];
  int tcols = N >> 5;
  int tr = tl / tcols, tc = tl - tr*tcols;
  const float* src = a.src[i];
  short* dst = a.dst[i];
  int r = t>>3, c4 = (t&7)*4;
  float4 v = *reinterpret_cast<const float4*>(src + (size_t)(tr*32+r)*N + tc*32 + c4);
  tile[r][c4+0]=v.x; tile[r][c4+1]=v.y; tile[r][c4+2]=v.z; tile[r][c4+3]=v.w;
  __syncthreads();
  short4 o = make_short4(f2b(tile[c4+0][r]), f2b(tile[c4+1][r]),
                         f2b(tile[c4+2][r]), f2b(tile[c4+3][r]));
  *reinterpret_cast<short4*>(dst + (size_t)(tc*32+r)*K + tr*32 + c4) = o;
}

// ---------------- MFMA GEMM v4: BK=64, XOR-swizzled LDS, XCD-swizzled grid
template<int EPI, int OBF, int WBF>
__global__ __launch_bounds__(256) void mgemm2(
    const short* __restrict__ A, const short* __restrict__ Bt,
    const float* __restrict__ bias, void* __restrict__ Cv,
    int M, int N, int Kd, short* __restrict__ Yb){
  __shared__ short As[128*64];
  __shared__ short Bs[128*64];
  int t=threadIdx.x, l=t&63, w=t>>6, lr=l&15, lk=l>>4;
  int wm=w>>1, wn=w&1;
  int bx = blockIdx.x, by = blockIdx.y;
  xcd_swz(bx, by);
  int m0=by*128, n0=bx*128;
  f32x4 acc[4][4];
  #pragma unroll
  for(int i=0;i<4;i++)
    #pragma unroll
    for(int j=0;j<4;j++) acc[i][j]=f32x4{0.f,0.f,0.f,0.f};
  int rsw = (l>>3)&7;
  for(int k0=0;k0<Kd;k0+=64){
    #pragma unroll
    for(int p=0;p<4;p++){
      int chunk = p*256 + t;
      int row = chunk>>3, qc = chunk&7;
      short* lbase = &As[(size_t)(p*256 + w*64)*8];
      gload16(A + (size_t)(m0+row)*Kd + k0 + (qc^rsw)*8, lbase);
    }
    #pragma unroll
    for(int p=0;p<4;p++){
      int chunk = p*256 + t;
      int row = chunk>>3, qc = chunk&7;
      short* lbase = &Bs[(size_t)(p*256 + w*64)*8];
      gload16(Bt + (size_t)(n0+row)*Kd + k0 + (qc^rsw)*8, lbase);
    }
    __syncthreads();
    #pragma unroll
    for(int ks=0;ks<2;ks++){
      short8 af[4], bfr[4];
      #pragma unroll
      for(int i=0;i<4;i++)
        af[i] = *reinterpret_cast<const short8*>(&As[(wm*64+i*16+lr)*64 + ((ks*32+lk*8)^((lr&7)<<3))]);
      #pragma unroll
      for(int j=0;j<4;j++)
        bfr[j] = *reinterpret_cast<const short8*>(&Bs[(wn*64+j*16+lr)*64 + ((ks*32+lk*8)^((lr&7)<<3))]);
      #pragma unroll
      for(int i=0;i<4;i++)
        #pragma unroll
        for(int j=0;j<4;j++) acc[i][j] = MFMA16(af[i], bfr[j], acc[i][j]);
    }
    __syncthreads();
  }
  #pragma unroll
  for(int i=0;i<4;i++){
    int gm0 = m0 + wm*64 + i*16 + lk*4;
    #pragma unroll
    for(int j=0;j<4;j++){
      int gc = n0 + wn*64 + j*16 + lr;
      float bs = bias[gc];
      #pragma unroll
      for(int r=0;r<4;r++){
        int gm = gm0 + r;
        if(gm<M){
          float vv = acc[i][j][r] + bs;
          if(EPI==2) vv = gelu_f(vv);
          size_t idx = (size_t)gm*N + gc;
          if(OBF){
            ((short*)Cv)[idx] = f2b(vv);
          } else {
            float* C = (float*)Cv;
            if(EPI==1) vv += C[idx];
            C[idx] = vv;
            if(WBF) Yb[idx] = f2b(vv);
          }
        }
      }
    }
  }
}

// ---------------- fused QKV GEMM + diag_k epilogue (BK=64, swizzled, XCD-swizzled)
__global__ __launch_bounds__(256) void qkv_gemm(
    const short* __restrict__ A, const short* __restrict__ Bt,
    const float* __restrict__ bq, const float* __restrict__ bk, const float* __restrict__ bv,
    short* __restrict__ qd, short* __restrict__ kd, short* __restrict__ vd,
    float* __restrict__ diagk, int M){
  __shared__ short As[128*64];
  __shared__ short Bs[128*64];
  int t=threadIdx.x, l=t&63, w=t>>6, lr=l&15, lk=l>>4;
  int wm=w>>1, wn=w&1;
  int bx = blockIdx.x, by = blockIdx.y;
  xcd_swz(bx, by);
  int m0=by*128, n0=bx*128;
  f32x4 acc[4][4];
  #pragma unroll
  for(int i=0;i<4;i++)
    #pragma unroll
    for(int j=0;j<4;j++) acc[i][j]=f32x4{0.f,0.f,0.f,0.f};
  int rsw = (l>>3)&7;
  for(int k0=0;k0<DIM;k0+=64){
    #pragma unroll
    for(int p=0;p<4;p++){
      int chunk = p*256 + t;
      int row = chunk>>3, qc = chunk&7;
      short* lbase = &As[(size_t)(p*256 + w*64)*8];
      gload16(A + (size_t)(m0+row)*DIM + k0 + (qc^rsw)*8, lbase);
    }
    #pragma unroll
    for(int p=0;p<4;p++){
      int chunk = p*256 + t;
      int row = chunk>>3, qc = chunk&7;
      short* lbase = &Bs[(size_t)(p*256 + w*64)*8];
      gload16(Bt + (size_t)(n0+row)*DIM + k0 + (qc^rsw)*8, lbase);
    }
    __syncthreads();
    #pragma unroll
    for(int ks=0;ks<2;ks++){
      short8 af[4], bfr[4];
      #pragma unroll
      for(int i=0;i<4;i++)
        af[i] = *reinterpret_cast<const short8*>(&As[(wm*64+i*16+lr)*64 + ((ks*32+lk*8)^((lr&7)<<3))]);
      #pragma unroll
      for(int j=0;j<4;j++)
        bfr[j] = *reinterpret_cast<const short8*>(&Bs[(wn*64+j*16+lr)*64 + ((ks*32+lk*8)^((lr&7)<<3))]);
      #pragma unroll
      for(int i=0;i<4;i++)
        #pragma unroll
        for(int j=0;j<4;j++) acc[i][j] = MFMA16(af[i], bfr[j], acc[i][j]);
    }
    __syncthreads();
  }
  bool isK = (bx==2) || (bx==3);
  int headq = ((n0 + wn*64) - 256) >> 6;
  #pragma unroll
  for(int i=0;i<4;i++){
    int gm0 = m0 + wm*64 + i*16 + lk*4;
    float sq[4] = {0.f,0.f,0.f,0.f};
    #pragma unroll
    for(int j=0;j<4;j++){
      int gc = n0 + wn*64 + j*16 + lr;
      int sel = gc >> 8, col = gc & 255;
      short* dst = (sel==0)? qd : ((sel==1)? kd : vd);
      const float* bp = (sel==0)? bq : ((sel==1)? bk : bv);
      float bs = bp[col];
      #pragma unroll
      for(int r=0;r<4;r++){
        int gm = gm0 + r;
        if(gm<M){
          short sv = f2b(acc[i][j][r] + bs);
          dst[(size_t)gm*DIM + col] = sv;
          if(isK){ float kv = b2f(sv); sq[r] += kv*kv; }
        }
      }
    }
    if(isK){
      #pragma unroll
      for(int r=0;r<4;r++){
        float s = sq[r];
        s += __shfl_xor(s,1); s += __shfl_xor(s,2);
        s += __shfl_xor(s,4); s += __shfl_xor(s,8);
        if(lr==0){
          int gm = gm0 + r;
          if(gm<M){
            int bb_ = gm / NSEQ, nn_ = gm - bb_*NSEQ;
            diagk[((size_t)(bb_*NH+headq))*NSEQ + nn_] = 0.0625f*s;
          }
        }
      }
    }
  }
}

// ---------------- projbf + kmax init
__global__ __launch_bounds__(256) void projprep_kernel(const float* __restrict__ proj,
    short* __restrict__ projbf, unsigned* __restrict__ kmax){
  int i = blockIdx.x*256 + threadIdx.x;
  if(i==0) *kmax = 0u;
  if(i < 320*64){
    int m = i>>6, d = i&63;
    float v = (m<MF)? proj[(size_t)m*DH + d]*NORMC : 0.f;
    projbf[i] = f2b(v);
  }
}

// ---------------- kside pass0 v2: 64-key chunks, gload16 swizzled, XCD-swizzled
__global__ __launch_bounds__(256) void kside_max(
    const short* __restrict__ kbf, const short* __restrict__ projbf,
    unsigned* __restrict__ kmax){
  __shared__ short kS[64*64];
  __shared__ float red[4];
  int t=threadIdx.x, l=t&63, w=t>>6, lr=l&15, lk=l>>4;
  int split = blockIdx.x, bh = blockIdx.y;
  xcd_swz(split, bh);
  int b=bh>>2, h=bh&3;
  int c0 = split*5, c1 = min(c0+5, 33);
  int nf = (w==3)?5:4;
  short8 apf[5][2];
  #pragma unroll
  for(int fi=0;fi<5;fi++){
    int fr = (fi<4)? (fi*4+w) : 16;
    #pragma unroll
    for(int ks=0;ks<2;ks++)
      apf[fi][ks] = *reinterpret_cast<const short8*>(projbf + (fr*16+lr)*64 + ks*32 + lk*8);
  }
  int rsw = (l>>3)&7;
  float lmax = -3.0e38f;
  for(int ch=c0; ch<c1; ++ch){
    int n0 = ch*64;
    __syncthreads();
    #pragma unroll
    for(int p=0;p<2;p++){
      int chunk = p*256 + t;
      int row = chunk>>3, qc = chunk&7;
      short* lbase = &kS[(size_t)(p*256 + w*64)*8];
      gload16(kbf + (size_t)(b*NSEQ + n0 + row)*DIM + h*DH + (qc^rsw)*8, lbase);
    }
    __syncthreads();
    for(int fi=0;fi<nf;fi++){
      int fr = (fi<4)? (fi*4+w) : 16;
      #pragma unroll
      for(int fn=0;fn<4;fn++){
        f32x4 xa = f32x4{0.f,0.f,0.f,0.f};
        #pragma unroll
        for(int ks=0;ks<2;ks++){
          short8 bk = *reinterpret_cast<const short8*>(&kS[(fn*16+lr)*64 + ((ks*32+lk*8)^((lr&7)<<3))]);
          xa = MFMA16(apf[fi][ks], bk, xa);
        }
        #pragma unroll
        for(int r=0;r<4;r++){
          int m = fr*16 + lk*4 + r;
          int n = n0 + fn*16 + lr;
          if(m<MF && n<NSEQ) lmax = fmaxf(lmax, xa[r]);
        }
      }
    }
  }
  float bm = blockMax256(lmax, red);
  if(t==0) atomicMax(kmax, fenc(bm));
}

// ---------------- kside pass1 v5 (round-17 LDS layout) + XCD swizzle
__global__ __launch_bounds__(256) void kside_ctx(
    const short* __restrict__ kbf, const short* __restrict__ vbf,
    const short* __restrict__ projbf, const float* __restrict__ diagk,
    const unsigned* __restrict__ kmax, float* __restrict__ ctxP){
  __shared__ short kS[64*64];
  __shared__ short vT[64*72];
  __shared__ short kfS[80*72];
  __shared__ float diagS[64];
  int t=threadIdx.x, l=t&63, w=t>>6, lr=l&15, lk=l>>4;
  int bxx = blockIdx.x, byy = blockIdx.y;
  xcd_swz(bxx, byy);
  int fb=bxx&3, qh=bxx>>2, bh=byy; int b=bh>>2, h=bh&3;
  int F0 = fb*5;
  int ch0 = qh*17, ch1 = min(33, ch0+17);
  float stab = fdec(*kmax);
  short8 apf0[2], apf1[2];
  #pragma unroll
  for(int ks=0;ks<2;ks++){
    apf0[ks] = *reinterpret_cast<const short8*>(projbf + ((F0+w)*16+lr)*64 + ks*32 + lk*8);
    apf1[ks] = *reinterpret_cast<const short8*>(projbf + ((F0+4)*16+lr)*64 + ks*32 + lk*8);
  }
  f32x4 ctx[5];
  #pragma unroll
  for(int f=0;f<5;f++) ctx[f]=f32x4{0.f,0.f,0.f,0.f};
  f32x4 ksc0 = f32x4{0.f,0.f,0.f,0.f};
  f32x4 ksc1 = f32x4{0.f,0.f,0.f,0.f};
  const short ONE=(short)0x3F80;
  const short8 ones8 = {ONE,ONE,ONE,ONE,ONE,ONE,ONE,ONE};
  int rsw = (l>>3)&7;
  for(int ch=ch0; ch<ch1; ++ch){
    int n0 = ch*64;
    __syncthreads();
    #pragma unroll
    for(int p=0;p<2;p++){
      int chunk = p*256 + t;
      int row = chunk>>3, qc = chunk&7;
      short* lbase = &kS[(size_t)(p*256 + w*64)*8];
      gload16(kbf + (size_t)(b*NSEQ + n0 + row)*DIM + h*DH + (qc^rsw)*8, lbase);
    }
    #pragma unroll
    for(int p=0;p<8;p++){
      int n2 = 2*w + 8*p;
      int dd = l;
      int gn0=n0+n2, gn1=gn0+1;
      short v0 = (gn0<NSEQ)? vbf[((size_t)(b*NSEQ+gn0))*DIM + h*DH + dd] : (short)0;
      short v1 = (gn1<NSEQ)? vbf[((size_t)(b*NSEQ+gn1))*DIM + h*DH + dd] : (short)0;
      *reinterpret_cast<short2*>(&vT[dd*72 + n2]) = make_short2(v0,v1);
    }
    if(t<64) diagS[t] = (n0+t<NSEQ)? diagk[(size_t)bh*NSEQ + n0+t] : 0.f;
    __syncthreads();
    #pragma unroll
    for(int fn=0;fn<4;fn++){
      f32x4 xa = f32x4{0.f,0.f,0.f,0.f};
      #pragma unroll
      for(int ks=0;ks<2;ks++){
        short8 bk = *reinterpret_cast<const short8*>(&kS[(fn*16+lr)*64 + ((ks*32+lk*8)^((lr&7)<<3))]);
        xa = MFMA16(apf0[ks], bk, xa);
      }
      float dgn = diagS[fn*16+lr];
      #pragma unroll
      for(int r=0;r<4;r++){
        int m = (F0+w)*16 + lk*4 + r;
        int n = n0 + fn*16 + lr;
        float kf = (m<MF && n<NSEQ)? RATIOC*(__expf(xa[r]-dgn-stab)+1e-4f) : 0.f;
        kfS[(w*16+lk*4+r)*72 + fn*16 + lr] = f2b(kf);
      }
    }
    if(w==0){
      #pragma unroll
      for(int fn=0;fn<4;fn++){
        f32x4 xa = f32x4{0.f,0.f,0.f,0.f};
        #pragma unroll
        for(int ks=0;ks<2;ks++){
          short8 bk = *reinterpret_cast<const short8*>(&kS[(fn*16+lr)*64 + ((ks*32+lk*8)^((lr&7)<<3))]);
          xa = MFMA16(apf1[ks], bk, xa);
        }
        float dgn = diagS[fn*16+lr];
        #pragma unroll
        for(int r=0;r<4;r++){
          int m = (F0+4)*16 + lk*4 + r;
          int n = n0 + fn*16 + lr;
          float kf = (m<MF && n<NSEQ)? RATIOC*(__expf(xa[r]-dgn-stab)+1e-4f) : 0.f;
          kfS[(64+lk*4+r)*72 + fn*16 + lr] = f2b(kf);
        }
      }
    }
    __syncthreads();
    #pragma unroll
    for(int ks2=0;ks2<2;ks2++){
      short8 bv = *reinterpret_cast<const short8*>(&vT[(w*16+lr)*72 + ks2*32 + lk*8]);
      short8 a0 = *reinterpret_cast<const short8*>(&kfS[(w*16+lr)*72 + ks2*32 + lk*8]);
      short8 a4 = *reinterpret_cast<const short8*>(&kfS[(64+lr)*72 + ks2*32 + lk*8]);
      ksc0 = MFMA16(a0, ones8, ksc0);
      ksc1 = MFMA16(a4, ones8, ksc1);
      #pragma unroll
      for(int fl=0;fl<5;fl++){
        short8 a_ = *reinterpret_cast<const short8*>(&kfS[(fl*16+lr)*72 + ks2*32 + lk*8]);
        ctx[fl] = MFMA16(a_, bv, ctx[fl]);
      }
    }
  }
  float* P = ctxP + ((size_t)(qh*128 + bh))*65*320;
  #pragma unroll
  for(int fl=0;fl<5;fl++){
    #pragma unroll
    for(int r=0;r<4;r++){
      int m = (F0+fl)*16 + lk*4 + r;
      P[(size_t)(w*16+lr)*320 + m] = ctx[fl][r];
    }
  }
  if(lr==0){
    #pragma unroll
    for(int r=0;r<4;r++){
      int m = (F0+w)*16 + lk*4 + r;
      P[(size_t)64*320 + m] = ksc0[r];
    }
    if(w==0){
      #pragma unroll
      for(int r=0;r<4;r++){
        int m = (F0+4)*16 + lk*4 + r;
        P[(size_t)64*320 + m] = ksc1[r];
      }
    }
  }
}

// ---------------- reduce 2 fp32 partials -> bf16 ctxT[bh][80][288]
__global__ __launch_bounds__(256) void ctx_reduce(const float* __restrict__ ctxP, short* __restrict__ ctxT){
  int row = blockIdx.x, bh = blockIdx.y, t = threadIdx.x;
  short* o = ctxT + ((size_t)bh*80 + row)*288;
  if(row < 65){
    const float* P0 = ctxP + ((size_t)bh*65 + row)*320;
    const float* P1 = ctxP + ((size_t)(128+bh)*65 + row)*320;
    for(int m=t; m<288; m+=256)
      o[m] = (m<272)? f2b(P0[m]+P1[m]) : (short)0;
  } else {
    for(int m=t; m<288; m+=256) o[m] = 0;
  }
}

// ---------------- qside (staged pipeline, qS aliased into qfS), XCD-swizzled
__global__ __launch_bounds__(256) void qside_mfma(
    const short* __restrict__ qbf, const short* __restrict__ projbf,
    const short* __restrict__ ctxT, short* __restrict__ obf){
  __shared__ short qfS[64*296];
  __shared__ float diagS[64];
  short* qS = qfS;
  int t=threadIdx.x, l=t&63, w=t>>6, lr=l&15, lk=l>>4;
  int bxx = blockIdx.x, byy = blockIdx.y;
  xcd_swz(bxx, byy);
  int n0 = bxx*64, bh = byy;
  int b = bh>>2, h = bh&3;
  const short8 z8 = {0,0,0,0,0,0,0,0};
  {
    int r = t>>2, c8 = (t&3)*16;
    int gn = n0 + r;
    float ssq = 0.f;
    #pragma unroll
    for(int i=0;i<2;i++){
      short8 v8 = z8;
      if(gn<NSEQ) v8 = *reinterpret_cast<const short8*>(qbf + ((size_t)(b*NSEQ+gn))*DIM + h*DH + c8 + i*8);
      #pragma unroll
      for(int u=0;u<8;u++){ float fv=b2f(v8[u]); ssq += fv*fv; }
      *reinterpret_cast<short8*>(&qS[r*72+c8+i*8]) = v8;
    }
    ssq += __shfl_xor(ssq,1); ssq += __shfl_xor(ssq,2);
    if((t&3)==0) diagS[r] = 0.0625f*ssq;
  }
  short8 aq[2];
  #pragma unroll
  for(int ks=0;ks<2;ks++) aq[ks] = *reinterpret_cast<const short8*>(&qS[(w*16+lr)*72 + ks*32 + lk*8]);
  float dg[4];
  #pragma unroll
  for(int r=0;r<4;r++) dg[r] = diagS[w*16 + lk*4 + r];
  __syncthreads();
  {
    int pr = w*16 + (l>>2), pc = 272 + (l&3)*4;
    #pragma unroll
    for(int i=0;i<4;i++) qfS[pr*296 + pc + i] = 0;
  }
  f32x4 acc[17];
  #pragma unroll
  for(int f=0;f<17;f++) acc[f]=f32x4{0.f,0.f,0.f,0.f};
  #pragma unroll
  for(int f=0;f<17;f++){
    #pragma unroll
    for(int ks=0;ks<2;ks++){
      short8 bp = *reinterpret_cast<const short8*>(projbf + (f*16+lr)*64 + ks*32 + lk*8);
      acc[f] = MFMA16(aq[ks], bp, acc[f]);
    }
  }
  float rmax[4];
  #pragma unroll
  for(int r=0;r<4;r++){
    float m = -3.0e38f;
    #pragma unroll
    for(int f=0;f<17;f++){
      float v = (f==16 && lr>=10)? -3.0e38f : acc[f][r];
      m = fmaxf(m,v);
    }
    m = fmaxf(m,__shfl_xor(m,1)); m = fmaxf(m,__shfl_xor(m,2));
    m = fmaxf(m,__shfl_xor(m,4)); m = fmaxf(m,__shfl_xor(m,8));
    rmax[r]=m;
  }
  #pragma unroll
  for(int f=0;f<17;f++)
    #pragma unroll
    for(int r=0;r<4;r++){
      float qv = RATIOC*(__expf(acc[f][r] - dg[r] - rmax[r]) + 1e-4f);
      qfS[(w*16+lk*4+r)*296 + f*16 + lr] = f2b(qv);
    }
  f32x4 pv[5];
  #pragma unroll
  for(int f=0;f<5;f++) pv[f]=f32x4{0.f,0.f,0.f,0.f};
  const short* cT = ctxT + (size_t)bh*80*288;
  for(int ks=0;ks<9;ks++){
    short8 a_ = *reinterpret_cast<const short8*>(&qfS[(w*16+lr)*296 + ks*32 + lk*8]);
    #pragma unroll
    for(int f=0;f<5;f++){
      short8 bb = *reinterpret_cast<const short8*>(cT + (f*16+lr)*288 + ks*32 + lk*8);
      pv[f] = MFMA16(a_, bb, pv[f]);
    }
  }
  #pragma unroll
  for(int r=0;r<4;r++){
    int gn = n0 + w*16 + lk*4 + r;
    if(gn>=NSEQ) continue;
    float den = __shfl(pv[4][r], (l & 48), 64);
    float inv = 1.0f/den;
    size_t obase = ((size_t)(b*NSEQ+gn))*DIM + h*DH;
    #pragma unroll
    for(int f=0;f<4;f++) obf[obase + f*16 + lr] = f2b(pv[f][r]*inv);
  }
}

// ---------------- small row projection (fp32)
__global__ __launch_bounds__(256) void rowproj_kernel(const float* __restrict__ src,
    const float* __restrict__ W, const float* __restrict__ bias,
    float* __restrict__ dst, int rowstride){
  __shared__ float rs[DIM];
  int b=blockIdx.x, t=threadIdx.x;
  rs[t]=src[(size_t)b*rowstride+t];
  __syncthreads();
  float s=bias[t];
  for(int j=0;j<DIM;j++) s += rs[j]*W[(size_t)j*DIM+t];
  dst[(size_t)b*DIM+t]=s;
}

// ---------------- final pooling: pass 1 — raw scores (grid 8 x NB)
__global__ __launch_bounds__(256) void pool_scores(const float* __restrict__ qfin,
    const short* __restrict__ kk, float* __restrict__ scb){
  __shared__ float qsh[DIM];
  int kc=blockIdx.x, b=blockIdx.y, t=threadIdx.x;
  qsh[t]=qfin[b*DIM+t];
  __syncthreads();
  int kidx = kc*256 + t;
  const short* kr = kk + ((size_t)(b*NSEQ+1+kidx))*DIM;
  float s=0;
  for(int j8=0;j8<32;j8++){
    short8 kv = *reinterpret_cast<const short8*>(kr + j8*8);
    #pragma unroll
    for(int u=0;u<8;u++) s += qsh[j8*8+u]*b2f(kv[u]);
  }
  scb[(size_t)b*KG + kidx] = s*0.0625f;
}

// ---------------- pool pass 2: per-b gmax/gsum
__global__ __launch_bounds__(256) void pool_sm(const float* __restrict__ scb,
    float* __restrict__ gms){
  __shared__ float red[4];
  int b=blockIdx.x, t=threadIdx.x;
  float ls[8]; float lmax=-3.4e38f;
  #pragma unroll
  for(int i=0;i<8;i++){
    ls[i] = scb[(size_t)b*KG + t + i*256];
    lmax = fmaxf(lmax, ls[i]);
  }
  float gmax=blockMax256(lmax,red);
  float lsum=0;
  #pragma unroll
  for(int i=0;i<8;i++) lsum += __expf(ls[i]-gmax);
  float gsum=blockSum256(lsum,red);
  if(t==0){ gms[b*2]=gmax; gms[b*2+1]=gsum; }
}

// ---------------- pool pass 3: partial PV (grid 8 x NB)
__global__ __launch_bounds__(256) void pool_pv2(const float* __restrict__ scb,
    const float* __restrict__ gms, const short* __restrict__ vv,
    float* __restrict__ part){
  __shared__ float es[256];
  int kc=blockIdx.x, b=blockIdx.y, t=threadIdx.x;
  float gmax = gms[b*2];
  es[t] = __expf(scb[(size_t)b*KG + kc*256 + t] - gmax);
  __syncthreads();
  float p=0;
  for(int i=0;i<256;i++){
    int kidx = kc*256 + i;
    p += es[i] * b2f(vv[((size_t)(b*NSEQ+1+kidx))*DIM + t]);
  }
  part[((size_t)(b*8)+kc)*DIM + t] = p;
}

// ---------------- pool pass 4: finish (grid NB)
__global__ __launch_bounds__(256) void pool_fin(const float* __restrict__ part,
    const float* __restrict__ gms, float* __restrict__ pooled){
  int b=blockIdx.x, t=threadIdx.x;
  float inv = 1.0f/gms[b*2+1];
  float s=0;
  #pragma unroll
  for(int kc=0;kc<8;kc++) s += part[((size_t)(b*8)+kc)*DIM + t];
  pooled[b*DIM+t] = s*inv;
}

extern "C" void kernel_launch(void* const* d_in, const int* in_sizes, int n_in,
                              void* d_out, int out_size, void* d_ws, size_t ws_size,
                              hipStream_t stream){
  const float* expr   =(const float*)d_in[0];
  const float* coords =(const float*)d_in[1];
  const float* gene_emb=(const float*)d_in[2];
  const float* pos_emb=(const float*)d_in[3];
  const float* val_w  =(const float*)d_in[4];
  const float* val_b  =(const float*)d_in[5];
  const float* val_g  =(const float*)d_in[6];
  const float* val_bb =(const float*)d_in[7];
  const float* sp_w   =(const float*)d_in[8];
  const float* sp_b   =(const float*)d_in[9];
  const float* sp_g   =(const float*)d_in[10];
  const float* sp_bb  =(const float*)d_in[11];
  const float* p_ln1_g=(const float*)d_in[12];
  const float* p_ln1_b=(const float*)d_in[13];
  const float* p_wq   =(const float*)d_in[14];
  const float* p_bq   =(const float*)d_in[15];
  const float* p_wk   =(const float*)d_in[16];
  const float* p_bk   =(const float*)d_in[17];
  const float* p_wv   =(const float*)d_in[18];
  const float* p_bv   =(const float*)d_in[19];
  const float* p_wo   =(const float*)d_in[20];
  const float* p_bo   =(const float*)d_in[21];
  const float* p_ln2_g=(const float*)d_in[22];
  const float* p_ln2_b=(const float*)d_in[23];
  const float* p_ff1_w=(const float*)d_in[24];
  const float* p_ff1_b=(const float*)d_in[25];
  const float* p_ff2_w=(const float*)d_in[26];
  const float* p_ff2_b=(const float*)d_in[27];
  const float* proj   =(const float*)d_in[28];
  const float* q_w    =(const float*)d_in[29];
  const float* q_b    =(const float*)d_in[30];
  const float* k_w    =(const float*)d_in[31];
  const float* k_b    =(const float*)d_in[32];
  const float* v_w    =(const float*)d_in[33];
  const float* v_b    =(const float*)d_in[34];
  const float* o_w    =(const float*)d_in[35];
  const float* o_b    =(const float*)d_in[36];
  float* out = (float*)d_out;

  const size_t BND = (size_t)BN*DIM;     // 16,785,408
  size_t needB = BND*4 + BND*2*4
               + ((size_t)NB*NH*NSEQ + 4 + 2*(size_t)NB*DIM)*4
               + ((size_t)20480 + 2949120 + 1703936)*2;
  if(ws_size < needB){
    hipMemsetAsync(d_out, 0, (size_t)out_size*sizeof(float), stream);
    return;
  }
  float* ws = (float*)d_ws;
  float* x  = ws;                                  // BND fp32
  short* ybf = (short*)(x + BND);
  short* qbf = ybf + BND;
  short* kbf = qbf + BND;
  short* vbf = kbf + BND;
  float* diagk = (float*)(vbf + BND);
  unsigned* kmax = (unsigned*)(diagk + (size_t)NB*NH*NSEQ);
  float* qfin   = (float*)(kmax+4);
  float* pooled = qfin + NB*DIM;
  short* projbf = (short*)(pooled + NB*DIM);       // 320*64
  short* ctxT   = projbf + 20480;                  // 128*80*288
  short* wt     = ctxT + (size_t)128*80*288;       // 1,703,936
  const size_t LW = 786432;
  float* ctxP = (float*)ybf;   // fp32 partials in dead ybf region
  float* scb  = diagk;         // pool scores scratch (65536 floats)
  float* gms  = diagk + 65536; // 64 floats
  float* ppart= gms + 64;      // 65536 floats

  // ---- fused weight prep
  {
    WPArgs a;
    short* wtkk = wt + 2*LW;
    short* wtvv = wtkk + 65536;
    const float* s10[10] = {p_wq, p_wk, p_wv, p_wo,
                            p_wq+(size_t)DIM*DIM, p_wk+(size_t)DIM*DIM,
                            p_wv+(size_t)DIM*DIM, p_wo+(size_t)DIM*DIM,
                            k_w, v_w};
    short* d10[10] = {wt, wt+65536, wt+131072, wt+196608,
                      wt+LW, wt+LW+65536, wt+LW+131072, wt+LW+196608,
                      wtkk, wtvv};
    int ti = 0;
    for(int i=0;i<10;i++){
      a.src[i]=s10[i]; a.dst[i]=d10[i]; a.K[i]=DIM; a.N[i]=DIM;
      a.ts[i]=ti; ti+=64;
    }
    const float* sff[4] = {p_ff1_w, p_ff2_w, p_ff1_w+(size_t)DIM*FFD, p_ff2_w+(size_t)FFD*DIM};
    short* dff[4] = {wt+262144, wt+524288, wt+LW+262144, wt+LW+524288};
    int Kff[4] = {DIM, FFD, DIM, FFD};
    int Nff[4] = {FFD, DIM, FFD, DIM};
    for(int i=0;i<4;i++){
      a.src[10+i]=sff[i]; a.dst[10+i]=dff[i]; a.K[10+i]=Kff[i]; a.N[10+i]=Nff[i];
      a.ts[10+i]=ti; ti+=256;
    }
    a.ts[14]=ti;
    wprep_fused<<<1664,256,0,stream>>>(a);
  }

  // embed + fused LN1(layer 0) -> ybf
  embed_kernel<<<BN/4,256,0,stream>>>(expr,coords,gene_emb,pos_emb,val_w,val_b,val_g,val_bb,
                                      sp_w,sp_b,sp_g,sp_bb, p_ln1_g, p_ln1_b, x, ybf);

  dim3 gdd(2, (BN+127)/128);
  dim3 gqkv(6, (BN+127)/128);
  dim3 gff1(8, (FFROWS2+127)/128);
  dim3 gff2(2, (FFROWS2+127)/128);
  dim3 gkm(7, NB*NH);
  dim3 gkc(8, NB*NH);
  dim3 gcr(80, NB*NH);
  dim3 gq((NSEQ+63)/64, NB*NH);
  dim3 gps(8, NB);
  short* wtkk = wt + 2*LW;
  short* wtvv = wtkk + 65536;

  for(int l=0;l<2;l++){
    short* wl = wt + (size_t)l*LW;
    if(l>0) ln_bf4<<<BN/4,256,0,stream>>>(x, p_ln1_g+l*DIM, p_ln1_b+l*DIM, ybf);
    qkv_gemm<<<gqkv,256,0,stream>>>(ybf, wl, p_bq+l*DIM, p_bk+l*DIM, p_bv+l*DIM,
                                    qbf, kbf, vbf, diagk, BN);
    projprep_kernel<<<80,256,0,stream>>>(proj + (size_t)l*MF*DH, projbf, kmax);
    kside_max<<<gkm,256,0,stream>>>(kbf, projbf, kmax);
    kside_ctx<<<gkc,256,0,stream>>>(kbf, vbf, projbf, diagk, kmax, ctxP);
    ctx_reduce<<<gcr,256,0,stream>>>(ctxP, ctxT);
    qside_mfma<<<gq,256,0,stream>>>(qbf, projbf, ctxT, kbf);   // o -> kbf
    mgemm2<1,0,0><<<gdd,256,0,stream>>>(kbf, wl+196608, p_bo+l*DIM, x, BN, DIM, DIM, nullptr);
    ln_bf4<<<BN/4,256,0,stream>>>(x, p_ln2_g+l*DIM, p_ln2_b+l*DIM, ybf);
    // FF 2-chunk: each chunk's intermediate = FFROWS2 x FFD = qbf+kbf exactly
    for(int c2=0;c2<2;c2++){
      size_t roff=(size_t)c2*FFROWS2;
      mgemm2<2,1,0><<<gff1,256,0,stream>>>(ybf+roff*DIM, wl+262144, p_ff1_b+l*FFD, qbf,
                                           FFROWS2, FFD, DIM, nullptr);
      if(l==1)
        mgemm2<1,0,1><<<gff2,256,0,stream>>>(qbf, wl+524288, p_ff2_b+l*DIM, x+roff*DIM,
                                             FFROWS2, DIM, FFD, ybf+roff*DIM);
      else
        mgemm2<1,0,0><<<gff2,256,0,stream>>>(qbf, wl+524288, p_ff2_b+l*DIM, x+roff*DIM,
                                             FFROWS2, DIM, FFD, nullptr);
    }
  }

  // final pooling attention (ybf already holds bf16(x) via WBF epilogue)
  mgemm2<0,1,0><<<gdd,256,0,stream>>>(ybf, wtkk, k_b, kbf, BN, DIM, DIM, nullptr);
  mgemm2<0,1,0><<<gdd,256,0,stream>>>(ybf, wtvv, v_b, vbf, BN, DIM, DIM, nullptr);
  rowproj_kernel<<<NB,256,0,stream>>>(x, q_w, q_b, qfin, NSEQ*DIM);
  pool_scores<<<gps,256,0,stream>>>(qfin, kbf, scb);
  pool_sm<<<NB,256,0,stream>>>(scb, gms);
  pool_pv2<<<gps,256,0,stream>>>(scb, gms, vbf, ppart);
  pool_fin<<<NB,256,0,stream>>>(ppart, gms, pooled);
  rowproj_kernel<<<NB,256,0,stream>>>(pooled, o_w, o_b, out, DIM);
}

// Round 20
// 1330.465 us; speedup vs baseline: 1.0902x; 1.0115x over previous
//
#include <hip/hip_runtime.h>
#include <hip/hip_bf16.h>
#include <math.h>

#define NB   32
#define KG   2048
#define NSEQ 2049
#define DIM  256
#define NH   4
#define DH   64
#define MF   266
#define FFD  1024
#define BN   (NB*NSEQ)          // 65568
#define FFROWS2 32784           // BN/2
#define NORMC 0.35355339059327376f   // 64^-0.25
#define RATIOC (1.0f/16.309506430300091f) // 266^-0.5

typedef __attribute__((ext_vector_type(8))) short short8;
typedef __attribute__((ext_vector_type(4))) float f32x4;
#define MFMA16(a,b,c) __builtin_amdgcn_mfma_f32_16x16x32_bf16(a,b,c,0,0,0)

__device__ __forceinline__ short f2b(float f){
  union{ __hip_bfloat16 h; short s;} u; u.h = __float2bfloat16(f); return u.s;
}
__device__ __forceinline__ float b2f(short s){
  union{ short s; __hip_bfloat16 h;} u; u.s = s; return __bfloat162float(u.h);
}
__device__ __forceinline__ float gelu_f(float x){
  return 0.5f*x*(1.0f+erff(x*0.70710678118654752f));
}
__device__ __forceinline__ void gload16(const short* g, short* l){
  __builtin_amdgcn_global_load_lds(
      (const __attribute__((address_space(1))) void*)g,
      (__attribute__((address_space(3))) void*)l, 16, 0, 0);
}
// bijective XCD-aware block swizzle (m204 chunked variant)
__device__ __forceinline__ void xcd_swz(int &bx, int &by){
  int nx = gridDim.x;
  int nwg = nx * gridDim.y;
  int flat = by*nx + bx;
  int q = nwg >> 3, r = nwg & 7;
  int x = flat & 7, base = flat >> 3;
  int swz = (x < r ? x*(q+1) : r*(q+1) + (x-r)*q) + base;
  bx = swz % nx; by = swz / nx;
}
__device__ __forceinline__ float waveSum(float v){
  #pragma unroll
  for(int o=32;o>0;o>>=1) v += __shfl_down(v,o);
  return v;   // lane 0 only
}
__device__ __forceinline__ float waveMax(float v){
  #pragma unroll
  for(int o=32;o>0;o>>=1) v = fmaxf(v,__shfl_down(v,o));
  return v;   // lane 0 only
}
__device__ __forceinline__ float xorSum64(float v){
  v += __shfl_xor(v,32); v += __shfl_xor(v,16); v += __shfl_xor(v,8);
  v += __shfl_xor(v,4);  v += __shfl_xor(v,2);  v += __shfl_xor(v,1);
  return v;   // exact, all lanes
}
__device__ __forceinline__ float blockSum256(float v, float* red){
  int lane = threadIdx.x & 63, wid = threadIdx.x >> 6;
  v = waveSum(v);
  __syncthreads();
  if(lane==0) red[wid]=v;
  __syncthreads();
  return red[0]+red[1]+red[2]+red[3];
}
__device__ __forceinline__ float blockMax256(float v, float* red){
  int lane = threadIdx.x & 63, wid = threadIdx.x >> 6;
  v = waveMax(v);
  __syncthreads();
  if(lane==0) red[wid]=v;
  __syncthreads();
  return fmaxf(fmaxf(red[0],red[1]),fmaxf(red[2],red[3]));
}
__device__ __forceinline__ unsigned fenc(float f){
  unsigned u = __float_as_uint(f);
  return (u & 0x80000000u) ? ~u : (u | 0x80000000u);
}
__device__ __forceinline__ float fdec(unsigned u){
  return (u & 0x80000000u) ? __uint_as_float(u & 0x7FFFFFFFu) : __uint_as_float(~u);
}

// ---------------- embed + fused LN1(layer0) -> ybf
__global__ __launch_bounds__(256) void embed_kernel(
    const float* __restrict__ expr, const float* __restrict__ coords,
    const float* __restrict__ gene_emb, const float* __restrict__ pos_emb,
    const float* __restrict__ val_w, const float* __restrict__ val_b,
    const float* __restrict__ val_g, const float* __restrict__ val_bb,
    const float* __restrict__ sp_w, const float* __restrict__ sp_b,
    const float* __restrict__ sp_g, const float* __restrict__ sp_bb,
    const float* __restrict__ ln_g, const float* __restrict__ ln_b,
    float* __restrict__ x, short* __restrict__ ybf){
  int w = threadIdx.x >> 6, l = threadIdx.x & 63;
  int row = blockIdx.x*4 + w;
  int b = row / NSEQ, n = row % NSEQ;
  int d0 = l*4;
  float4 v;
  if(n==0){
    float c0 = coords[b*2], c1 = coords[b*2+1];
    float4 w0 = *reinterpret_cast<const float4*>(sp_w + d0);
    float4 w1 = *reinterpret_cast<const float4*>(sp_w + DIM + d0);
    float4 bb = *reinterpret_cast<const float4*>(sp_b + d0);
    v = make_float4(c0*w0.x+c1*w1.x+bb.x, c0*w0.y+c1*w1.y+bb.y,
                    c0*w0.z+c1*w1.z+bb.z, c0*w0.w+c1*w1.w+bb.w);
  } else {
    float e = expr[(size_t)b*KG + (n-1)];
    float4 vw = *reinterpret_cast<const float4*>(val_w + d0);
    float4 vb = *reinterpret_cast<const float4*>(val_b + d0);
    v = make_float4(e*vw.x+vb.x, e*vw.y+vb.y, e*vw.z+vb.z, e*vw.w+vb.w);
  }
  float mu = xorSum64(v.x+v.y+v.z+v.w)*(1.0f/DIM);
  float cx=v.x-mu, cy=v.y-mu, cz=v.z-mu, cw=v.w-mu;
  float var = xorSum64(cx*cx+cy*cy+cz*cz+cw*cw)*(1.0f/DIM);
  float r = rsqrtf(var + 1e-5f);
  float4 g  = (n==0)? *reinterpret_cast<const float4*>(sp_g + d0)
                    : *reinterpret_cast<const float4*>(val_g + d0);
  float4 be = (n==0)? *reinterpret_cast<const float4*>(sp_bb + d0)
                    : *reinterpret_cast<const float4*>(val_bb + d0);
  float4 h = make_float4(gelu_f(cx*r*g.x+be.x), gelu_f(cy*r*g.y+be.y),
                         gelu_f(cz*r*g.z+be.z), gelu_f(cw*r*g.w+be.w));
  if(n!=0){
    float4 ge = *reinterpret_cast<const float4*>(gene_emb + (size_t)(n-1)*DIM + d0);
    float4 pe = *reinterpret_cast<const float4*>(pos_emb  + (size_t)(n-1)*DIM + d0);
    h.x += ge.x+pe.x; h.y += ge.y+pe.y; h.z += ge.z+pe.z; h.w += ge.w+pe.w;
  }
  *reinterpret_cast<float4*>(x + (size_t)row*DIM + d0) = h;
  float s2 = xorSum64(h.x+h.y+h.z+h.w);
  float mu2 = s2*(1.0f/DIM);
  float c2x=h.x-mu2, c2y=h.y-mu2, c2z=h.z-mu2, c2w=h.w-mu2;
  float var2 = xorSum64(c2x*c2x+c2y*c2y+c2z*c2z+c2w*c2w)*(1.0f/DIM);
  float r2 = rsqrtf(var2+1e-5f);
  const float4 gv = *reinterpret_cast<const float4*>(ln_g + d0);
  const float4 bv = *reinterpret_cast<const float4*>(ln_b + d0);
  short4 o = make_short4(f2b(c2x*r2*gv.x+bv.x), f2b(c2y*r2*gv.y+bv.y),
                         f2b(c2z*r2*gv.z+bv.z), f2b(c2w*r2*gv.w+bv.w));
  *reinterpret_cast<short4*>(ybf + (size_t)row*DIM + d0) = o;
}

// ---------------- LN -> bf16, wave-per-row, xor-exact
__global__ __launch_bounds__(256) void ln_bf4(const float* __restrict__ xin,
    const float* __restrict__ g, const float* __restrict__ bb, short* __restrict__ ybf){
  int w = threadIdx.x >> 6, l = threadIdx.x & 63;
  int row = blockIdx.x*4 + w;
  const float* xr = xin + (size_t)row*DIM;
  float4 v = *reinterpret_cast<const float4*>(xr + l*4);
  float s = xorSum64(v.x+v.y+v.z+v.w);
  float mu = s*(1.0f/DIM);
  float cx=v.x-mu, cy=v.y-mu, cz=v.z-mu, cw=v.w-mu;
  float var = xorSum64(cx*cx+cy*cy+cz*cz+cw*cw)*(1.0f/DIM);
  float r = rsqrtf(var+1e-5f);
  const float4 gv = *reinterpret_cast<const float4*>(g + l*4);
  const float4 bv = *reinterpret_cast<const float4*>(bb + l*4);
  short4 o = make_short4(f2b(cx*r*gv.x+bv.x), f2b(cy*r*gv.y+bv.y),
                         f2b(cz*r*gv.z+bv.z), f2b(cw*r*gv.w+bv.w));
  *reinterpret_cast<short4*>(ybf + (size_t)row*DIM + l*4) = o;
}

// ---------------- fused weight prep: 14 matrices, 32x32 LDS tile transpose
#define NW 14
struct WPArgs {
  const float* src[NW];
  short* dst[NW];
  int K[NW], N[NW];
  int ts[NW+1];
};
__global__ __launch_bounds__(256) void wprep_fused(WPArgs a){
  __shared__ float tile[32][33];
  int bx = blockIdx.x, t = threadIdx.x;
  int i = 0;
  while(bx >= a.ts[i+1]) i++;
  int tl = bx - a.ts[i];
  int N = a.N[i], K = a.K[i];
  int tcols = N >> 5;
  int tr = tl / tcols, tc = tl - tr*tcols;
  const float* src = a.src[i];
  short* dst = a.dst[i];
  int r = t>>3, c4 = (t&7)*4;
  float4 v = *reinterpret_cast<const float4*>(src + (size_t)(tr*32+r)*N + tc*32 + c4);
  tile[r][c4+0]=v.x; tile[r][c4+1]=v.y; tile[r][c4+2]=v.z; tile[r][c4+3]=v.w;
  __syncthreads();
  short4 o = make_short4(f2b(tile[c4+0][r]), f2b(tile[c4+1][r]),
                         f2b(tile[c4+2][r]), f2b(tile[c4+3][r]));
  *reinterpret_cast<short4*>(dst + (size_t)(tc*32+r)*K + tr*32 + c4) = o;
}

// ---------------- MFMA GEMM v4: BK=64, XOR-swizzled LDS, XCD-swizzled grid
template<int EPI, int OBF, int WBF>
__global__ __launch_bounds__(256) void mgemm2(
    const short* __restrict__ A, const short* __restrict__ Bt,
    const float* __restrict__ bias, void* __restrict__ Cv,
    int M, int N, int Kd, short* __restrict__ Yb){
  __shared__ short As[128*64];
  __shared__ short Bs[128*64];
  int t=threadIdx.x, l=t&63, w=t>>6, lr=l&15, lk=l>>4;
  int wm=w>>1, wn=w&1;
  int bx = blockIdx.x, by = blockIdx.y;
  xcd_swz(bx, by);
  int m0=by*128, n0=bx*128;
  f32x4 acc[4][4];
  #pragma unroll
  for(int i=0;i<4;i++)
    #pragma unroll
    for(int j=0;j<4;j++) acc[i][j]=f32x4{0.f,0.f,0.f,0.f};
  int rsw = (l>>3)&7;
  for(int k0=0;k0<Kd;k0+=64){
    #pragma unroll
    for(int p=0;p<4;p++){
      int chunk = p*256 + t;
      int row = chunk>>3, qc = chunk&7;
      short* lbase = &As[(size_t)(p*256 + w*64)*8];
      gload16(A + (size_t)(m0+row)*Kd + k0 + (qc^rsw)*8, lbase);
    }
    #pragma unroll
    for(int p=0;p<4;p++){
      int chunk = p*256 + t;
      int row = chunk>>3, qc = chunk&7;
      short* lbase = &Bs[(size_t)(p*256 + w*64)*8];
      gload16(Bt + (size_t)(n0+row)*Kd + k0 + (qc^rsw)*8, lbase);
    }
    __syncthreads();
    #pragma unroll
    for(int ks=0;ks<2;ks++){
      short8 af[4], bfr[4];
      #pragma unroll
      for(int i=0;i<4;i++)
        af[i] = *reinterpret_cast<const short8*>(&As[(wm*64+i*16+lr)*64 + ((ks*32+lk*8)^((lr&7)<<3))]);
      #pragma unroll
      for(int j=0;j<4;j++)
        bfr[j] = *reinterpret_cast<const short8*>(&Bs[(wn*64+j*16+lr)*64 + ((ks*32+lk*8)^((lr&7)<<3))]);
      #pragma unroll
      for(int i=0;i<4;i++)
        #pragma unroll
        for(int j=0;j<4;j++) acc[i][j] = MFMA16(af[i], bfr[j], acc[i][j]);
    }
    __syncthreads();
  }
  #pragma unroll
  for(int i=0;i<4;i++){
    int gm0 = m0 + wm*64 + i*16 + lk*4;
    #pragma unroll
    for(int j=0;j<4;j++){
      int gc = n0 + wn*64 + j*16 + lr;
      float bs = bias[gc];
      #pragma unroll
      for(int r=0;r<4;r++){
        int gm = gm0 + r;
        if(gm<M){
          float vv = acc[i][j][r] + bs;
          if(EPI==2) vv = gelu_f(vv);
          size_t idx = (size_t)gm*N + gc;
          if(OBF){
            ((short*)Cv)[idx] = f2b(vv);
          } else {
            float* C = (float*)Cv;
            if(EPI==1) vv += C[idx];
            C[idx] = vv;
            if(WBF) Yb[idx] = f2b(vv);
          }
        }
      }
    }
  }
}

// ---------------- fused QKV GEMM + diag_k epilogue (BK=64, swizzled, XCD-swizzled)
__global__ __launch_bounds__(256) void qkv_gemm(
    const short* __restrict__ A, const short* __restrict__ Bt,
    const float* __restrict__ bq, const float* __restrict__ bk, const float* __restrict__ bv,
    short* __restrict__ qd, short* __restrict__ kd, short* __restrict__ vd,
    float* __restrict__ diagk, int M){
  __shared__ short As[128*64];
  __shared__ short Bs[128*64];
  int t=threadIdx.x, l=t&63, w=t>>6, lr=l&15, lk=l>>4;
  int wm=w>>1, wn=w&1;
  int bx = blockIdx.x, by = blockIdx.y;
  xcd_swz(bx, by);
  int m0=by*128, n0=bx*128;
  f32x4 acc[4][4];
  #pragma unroll
  for(int i=0;i<4;i++)
    #pragma unroll
    for(int j=0;j<4;j++) acc[i][j]=f32x4{0.f,0.f,0.f,0.f};
  int rsw = (l>>3)&7;
  for(int k0=0;k0<DIM;k0+=64){
    #pragma unroll
    for(int p=0;p<4;p++){
      int chunk = p*256 + t;
      int row = chunk>>3, qc = chunk&7;
      short* lbase = &As[(size_t)(p*256 + w*64)*8];
      gload16(A + (size_t)(m0+row)*DIM + k0 + (qc^rsw)*8, lbase);
    }
    #pragma unroll
    for(int p=0;p<4;p++){
      int chunk = p*256 + t;
      int row = chunk>>3, qc = chunk&7;
      short* lbase = &Bs[(size_t)(p*256 + w*64)*8];
      gload16(Bt + (size_t)(n0+row)*DIM + k0 + (qc^rsw)*8, lbase);
    }
    __syncthreads();
    #pragma unroll
    for(int ks=0;ks<2;ks++){
      short8 af[4], bfr[4];
      #pragma unroll
      for(int i=0;i<4;i++)
        af[i] = *reinterpret_cast<const short8*>(&As[(wm*64+i*16+lr)*64 + ((ks*32+lk*8)^((lr&7)<<3))]);
      #pragma unroll
      for(int j=0;j<4;j++)
        bfr[j] = *reinterpret_cast<const short8*>(&Bs[(wn*64+j*16+lr)*64 + ((ks*32+lk*8)^((lr&7)<<3))]);
      #pragma unroll
      for(int i=0;i<4;i++)
        #pragma unroll
        for(int j=0;j<4;j++) acc[i][j] = MFMA16(af[i], bfr[j], acc[i][j]);
    }
    __syncthreads();
  }
  bool isK = (bx==2) || (bx==3);
  int headq = ((n0 + wn*64) - 256) >> 6;
  #pragma unroll
  for(int i=0;i<4;i++){
    int gm0 = m0 + wm*64 + i*16 + lk*4;
    float sq[4] = {0.f,0.f,0.f,0.f};
    #pragma unroll
    for(int j=0;j<4;j++){
      int gc = n0 + wn*64 + j*16 + lr;
      int sel = gc >> 8, col = gc & 255;
      short* dst = (sel==0)? qd : ((sel==1)? kd : vd);
      const float* bp = (sel==0)? bq : ((sel==1)? bk : bv);
      float bs = bp[col];
      #pragma unroll
      for(int r=0;r<4;r++){
        int gm = gm0 + r;
        if(gm<M){
          short sv = f2b(acc[i][j][r] + bs);
          dst[(size_t)gm*DIM + col] = sv;
          if(isK){ float kv = b2f(sv); sq[r] += kv*kv; }
        }
      }
    }
    if(isK){
      #pragma unroll
      for(int r=0;r<4;r++){
        float s = sq[r];
        s += __shfl_xor(s,1); s += __shfl_xor(s,2);
        s += __shfl_xor(s,4); s += __shfl_xor(s,8);
        if(lr==0){
          int gm = gm0 + r;
          if(gm<M){
            int bb_ = gm / NSEQ, nn_ = gm - bb_*NSEQ;
            diagk[((size_t)(bb_*NH+headq))*NSEQ + nn_] = 0.0625f*s;
          }
        }
      }
    }
  }
}

// ---------------- projbf + kmax init
__global__ __launch_bounds__(256) void projprep_kernel(const float* __restrict__ proj,
    short* __restrict__ projbf, unsigned* __restrict__ kmax){
  int i = blockIdx.x*256 + threadIdx.x;
  if(i==0) *kmax = 0u;
  if(i < 320*64){
    int m = i>>6, d = i&63;
    float v = (m<MF)? proj[(size_t)m*DH + d]*NORMC : 0.f;
    projbf[i] = f2b(v);
  }
}

// ---------------- kside pass0 v2: 64-key chunks, gload16 swizzled, XCD-swizzled
__global__ __launch_bounds__(256) void kside_max(
    const short* __restrict__ kbf, const short* __restrict__ projbf,
    unsigned* __restrict__ kmax){
  __shared__ short kS[64*64];
  __shared__ float red[4];
  int t=threadIdx.x, l=t&63, w=t>>6, lr=l&15, lk=l>>4;
  int split = blockIdx.x, bh = blockIdx.y;
  xcd_swz(split, bh);
  int b=bh>>2, h=bh&3;
  int c0 = split*5, c1 = min(c0+5, 33);
  int nf = (w==3)?5:4;
  short8 apf[5][2];
  #pragma unroll
  for(int fi=0;fi<5;fi++){
    int fr = (fi<4)? (fi*4+w) : 16;
    #pragma unroll
    for(int ks=0;ks<2;ks++)
      apf[fi][ks] = *reinterpret_cast<const short8*>(projbf + (fr*16+lr)*64 + ks*32 + lk*8);
  }
  int rsw = (l>>3)&7;
  float lmax = -3.0e38f;
  for(int ch=c0; ch<c1; ++ch){
    int n0 = ch*64;
    __syncthreads();
    #pragma unroll
    for(int p=0;p<2;p++){
      int chunk = p*256 + t;
      int row = chunk>>3, qc = chunk&7;
      short* lbase = &kS[(size_t)(p*256 + w*64)*8];
      gload16(kbf + (size_t)(b*NSEQ + n0 + row)*DIM + h*DH + (qc^rsw)*8, lbase);
    }
    __syncthreads();
    for(int fi=0;fi<nf;fi++){
      int fr = (fi<4)? (fi*4+w) : 16;
      #pragma unroll
      for(int fn=0;fn<4;fn++){
        f32x4 xa = f32x4{0.f,0.f,0.f,0.f};
        #pragma unroll
        for(int ks=0;ks<2;ks++){
          short8 bk = *reinterpret_cast<const short8*>(&kS[(fn*16+lr)*64 + ((ks*32+lk*8)^((lr&7)<<3))]);
          xa = MFMA16(apf[fi][ks], bk, xa);
        }
        #pragma unroll
        for(int r=0;r<4;r++){
          int m = fr*16 + lk*4 + r;
          int n = n0 + fn*16 + lr;
          if(m<MF && n<NSEQ) lmax = fmaxf(lmax, xa[r]);
        }
      }
    }
  }
  float bm = blockMax256(lmax, red);
  if(t==0) atomicMax(kmax, fenc(bm));
}

// ---------------- kside pass1 v5 (round-17 LDS layout) + XCD swizzle
__global__ __launch_bounds__(256) void kside_ctx(
    const short* __restrict__ kbf, const short* __restrict__ vbf,
    const short* __restrict__ projbf, const float* __restrict__ diagk,
    const unsigned* __restrict__ kmax, float* __restrict__ ctxP){
  __shared__ short kS[64*64];
  __shared__ short vT[64*72];
  __shared__ short kfS[80*72];
  __shared__ float diagS[64];
  int t=threadIdx.x, l=t&63, w=t>>6, lr=l&15, lk=l>>4;
  int bxx = blockIdx.x, byy = blockIdx.y;
  xcd_swz(bxx, byy);
  int fb=bxx&3, qh=bxx>>2, bh=byy; int b=bh>>2, h=bh&3;
  int F0 = fb*5;
  int ch0 = qh*17, ch1 = min(33, ch0+17);
  float stab = fdec(*kmax);
  short8 apf0[2], apf1[2];
  #pragma unroll
  for(int ks=0;ks<2;ks++){
    apf0[ks] = *reinterpret_cast<const short8*>(projbf + ((F0+w)*16+lr)*64 + ks*32 + lk*8);
    apf1[ks] = *reinterpret_cast<const short8*>(projbf + ((F0+4)*16+lr)*64 + ks*32 + lk*8);
  }
  f32x4 ctx[5];
  #pragma unroll
  for(int f=0;f<5;f++) ctx[f]=f32x4{0.f,0.f,0.f,0.f};
  f32x4 ksc0 = f32x4{0.f,0.f,0.f,0.f};
  f32x4 ksc1 = f32x4{0.f,0.f,0.f,0.f};
  const short ONE=(short)0x3F80;
  const short8 ones8 = {ONE,ONE,ONE,ONE,ONE,ONE,ONE,ONE};
  int rsw = (l>>3)&7;
  for(int ch=ch0; ch<ch1; ++ch){
    int n0 = ch*64;
    __syncthreads();
    #pragma unroll
    for(int p=0;p<2;p++){
      int chunk = p*256 + t;
      int row = chunk>>3, qc = chunk&7;
      short* lbase = &kS[(size_t)(p*256 + w*64)*8];
      gload16(kbf + (size_t)(b*NSEQ + n0 + row)*DIM + h*DH + (qc^rsw)*8, lbase);
    }
    #pragma unroll
    for(int p=0;p<8;p++){
      int n2 = 2*w + 8*p;
      int dd = l;
      int gn0=n0+n2, gn1=gn0+1;
      short v0 = (gn0<NSEQ)? vbf[((size_t)(b*NSEQ+gn0))*DIM + h*DH + dd] : (short)0;
      short v1 = (gn1<NSEQ)? vbf[((size_t)(b*NSEQ+gn1))*DIM + h*DH + dd] : (short)0;
      *reinterpret_cast<short2*>(&vT[dd*72 + n2]) = make_short2(v0,v1);
    }
    if(t<64) diagS[t] = (n0+t<NSEQ)? diagk[(size_t)bh*NSEQ + n0+t] : 0.f;
    __syncthreads();
    #pragma unroll
    for(int fn=0;fn<4;fn++){
      f32x4 xa = f32x4{0.f,0.f,0.f,0.f};
      #pragma unroll
      for(int ks=0;ks<2;ks++){
        short8 bk = *reinterpret_cast<const short8*>(&kS[(fn*16+lr)*64 + ((ks*32+lk*8)^((lr&7)<<3))]);
        xa = MFMA16(apf0[ks], bk, xa);
      }
      float dgn = diagS[fn*16+lr];
      #pragma unroll
      for(int r=0;r<4;r++){
        int m = (F0+w)*16 + lk*4 + r;
        int n = n0 + fn*16 + lr;
        float kf = (m<MF && n<NSEQ)? RATIOC*(__expf(xa[r]-dgn-stab)+1e-4f) : 0.f;
        kfS[(w*16+lk*4+r)*72 + fn*16 + lr] = f2b(kf);
      }
    }
    if(w==0){
      #pragma unroll
      for(int fn=0;fn<4;fn++){
        f32x4 xa = f32x4{0.f,0.f,0.f,0.f};
        #pragma unroll
        for(int ks=0;ks<2;ks++){
          short8 bk = *reinterpret_cast<const short8*>(&kS[(fn*16+lr)*64 + ((ks*32+lk*8)^((lr&7)<<3))]);
          xa = MFMA16(apf1[ks], bk, xa);
        }
        float dgn = diagS[fn*16+lr];
        #pragma unroll
        for(int r=0;r<4;r++){
          int m = (F0+4)*16 + lk*4 + r;
          int n = n0 + fn*16 + lr;
          float kf = (m<MF && n<NSEQ)? RATIOC*(__expf(xa[r]-dgn-stab)+1e-4f) : 0.f;
          kfS[(64+lk*4+r)*72 + fn*16 + lr] = f2b(kf);
        }
      }
    }
    __syncthreads();
    #pragma unroll
    for(int ks2=0;ks2<2;ks2++){
      short8 bv = *reinterpret_cast<const short8*>(&vT[(w*16+lr)*72 + ks2*32 + lk*8]);
      short8 a0 = *reinterpret_cast<const short8*>(&kfS[(w*16+lr)*72 + ks2*32 + lk*8]);
      short8 a4 = *reinterpret_cast<const short8*>(&kfS[(64+lr)*72 + ks2*32 + lk*8]);
      ksc0 = MFMA16(a0, ones8, ksc0);
      ksc1 = MFMA16(a4, ones8, ksc1);
      #pragma unroll
      for(int fl=0;fl<5;fl++){
        short8 a_ = *reinterpret_cast<const short8*>(&kfS[(fl*16+lr)*72 + ks2*32 + lk*8]);
        ctx[fl] = MFMA16(a_, bv, ctx[fl]);
      }
    }
  }
  float* P = ctxP + ((size_t)(qh*128 + bh))*65*320;
  #pragma unroll
  for(int fl=0;fl<5;fl++){
    #pragma unroll
    for(int r=0;r<4;r++){
      int m = (F0+fl)*16 + lk*4 + r;
      P[(size_t)(w*16+lr)*320 + m] = ctx[fl][r];
    }
  }
  if(lr==0){
    #pragma unroll
    for(int r=0;r<4;r++){
      int m = (F0+w)*16 + lk*4 + r;
      P[(size_t)64*320 + m] = ksc0[r];
    }
    if(w==0){
      #pragma unroll
      for(int r=0;r<4;r++){
        int m = (F0+4)*16 + lk*4 + r;
        P[(size_t)64*320 + m] = ksc1[r];
      }
    }
  }
}

// ---------------- reduce 2 fp32 partials -> bf16 ctxT[bh][80][288]
__global__ __launch_bounds__(256) void ctx_reduce(const float* __restrict__ ctxP, short* __restrict__ ctxT){
  int row = blockIdx.x, bh = blockIdx.y, t = threadIdx.x;
  short* o = ctxT + ((size_t)bh*80 + row)*288;
  if(row < 65){
    const float* P0 = ctxP + ((size_t)bh*65 + row)*320;
    const float* P1 = ctxP + ((size_t)(128+bh)*65 + row)*320;
    for(int m=t; m<288; m+=256)
      o[m] = (m<272)? f2b(P0[m]+P1[m]) : (short)0;
  } else {
    for(int m=t; m<288; m+=256) o[m] = 0;
  }
}

// ---------------- qside (staged pipeline, qS aliased into qfS), XCD-swizzled
__global__ __launch_bounds__(256) void qside_mfma(
    const short* __restrict__ qbf, const short* __restrict__ projbf,
    const short* __restrict__ ctxT, short* __restrict__ obf){
  __shared__ short qfS[64*296];
  __shared__ float diagS[64];
  short* qS = qfS;
  int t=threadIdx.x, l=t&63, w=t>>6, lr=l&15, lk=l>>4;
  int bxx = blockIdx.x, byy = blockIdx.y;
  xcd_swz(bxx, byy);
  int n0 = bxx*64, bh = byy;
  int b = bh>>2, h = bh&3;
  const short8 z8 = {0,0,0,0,0,0,0,0};
  {
    int r = t>>2, c8 = (t&3)*16;
    int gn = n0 + r;
    float ssq = 0.f;
    #pragma unroll
    for(int i=0;i<2;i++){
      short8 v8 = z8;
      if(gn<NSEQ) v8 = *reinterpret_cast<const short8*>(qbf + ((size_t)(b*NSEQ+gn))*DIM + h*DH + c8 + i*8);
      #pragma unroll
      for(int u=0;u<8;u++){ float fv=b2f(v8[u]); ssq += fv*fv; }
      *reinterpret_cast<short8*>(&qS[r*72+c8+i*8]) = v8;
    }
    ssq += __shfl_xor(ssq,1); ssq += __shfl_xor(ssq,2);
    if((t&3)==0) diagS[r] = 0.0625f*ssq;
  }
  short8 aq[2];
  #pragma unroll
  for(int ks=0;ks<2;ks++) aq[ks] = *reinterpret_cast<const short8*>(&qS[(w*16+lr)*72 + ks*32 + lk*8]);
  float dg[4];
  #pragma unroll
  for(int r=0;r<4;r++) dg[r] = diagS[w*16 + lk*4 + r];
  __syncthreads();
  {
    int pr = w*16 + (l>>2), pc = 272 + (l&3)*4;
    #pragma unroll
    for(int i=0;i<4;i++) qfS[pr*296 + pc + i] = 0;
  }
  f32x4 acc[17];
  #pragma unroll
  for(int f=0;f<17;f++) acc[f]=f32x4{0.f,0.f,0.f,0.f};
  #pragma unroll
  for(int f=0;f<17;f++){
    #pragma unroll
    for(int ks=0;ks<2;ks++){
      short8 bp = *reinterpret_cast<const short8*>(projbf + (f*16+lr)*64 + ks*32 + lk*8);
      acc[f] = MFMA16(aq[ks], bp, acc[f]);
    }
  }
  float rmax[4];
  #pragma unroll
  for(int r=0;r<4;r++){
    float m = -3.0e38f;
    #pragma unroll
    for(int f=0;f<17;f++){
      float v = (f==16 && lr>=10)? -3.0e38f : acc[f][r];
      m = fmaxf(m,v);
    }
    m = fmaxf(m,__shfl_xor(m,1)); m = fmaxf(m,__shfl_xor(m,2));
    m = fmaxf(m,__shfl_xor(m,4)); m = fmaxf(m,__shfl_xor(m,8));
    rmax[r]=m;
  }
  #pragma unroll
  for(int f=0;f<17;f++)
    #pragma unroll
    for(int r=0;r<4;r++){
      float qv = RATIOC*(__expf(acc[f][r] - dg[r] - rmax[r]) + 1e-4f);
      qfS[(w*16+lk*4+r)*296 + f*16 + lr] = f2b(qv);
    }
  f32x4 pv[5];
  #pragma unroll
  for(int f=0;f<5;f++) pv[f]=f32x4{0.f,0.f,0.f,0.f};
  const short* cT = ctxT + (size_t)bh*80*288;
  #pragma unroll 2
  for(int ks=0;ks<9;ks++){
    short8 a_ = *reinterpret_cast<const short8*>(&qfS[(w*16+lr)*296 + ks*32 + lk*8]);
    #pragma unroll
    for(int f=0;f<5;f++){
      short8 bb = *reinterpret_cast<const short8*>(cT + (f*16+lr)*288 + ks*32 + lk*8);
      pv[f] = MFMA16(a_, bb, pv[f]);
    }
  }
  #pragma unroll
  for(int r=0;r<4;r++){
    int gn = n0 + w*16 + lk*4 + r;
    if(gn>=NSEQ) continue;
    float den = __shfl(pv[4][r], (l & 48), 64);
    float inv = 1.0f/den;
    size_t obase = ((size_t)(b*NSEQ+gn))*DIM + h*DH;
    #pragma unroll
    for(int f=0;f<4;f++) obf[obase + f*16 + lr] = f2b(pv[f][r]*inv);
  }
}

// ---------------- small row projection (fp32)
__global__ __launch_bounds__(256) void rowproj_kernel(const float* __restrict__ src,
    const float* __restrict__ W, const float* __restrict__ bias,
    float* __restrict__ dst, int rowstride){
  __shared__ float rs[DIM];
  int b=blockIdx.x, t=threadIdx.x;
  rs[t]=src[(size_t)b*rowstride+t];
  __syncthreads();
  float s=bias[t];
  for(int j=0;j<DIM;j++) s += rs[j]*W[(size_t)j*DIM+t];
  dst[(size_t)b*DIM+t]=s;
}

// ---------------- final pooling: pass 1 — raw scores (grid 8 x NB)
__global__ __launch_bounds__(256) void pool_scores(const float* __restrict__ qfin,
    const short* __restrict__ kk, float* __restrict__ scb){
  __shared__ float qsh[DIM];
  int kc=blockIdx.x, b=blockIdx.y, t=threadIdx.x;
  qsh[t]=qfin[b*DIM+t];
  __syncthreads();
  int kidx = kc*256 + t;
  const short* kr = kk + ((size_t)(b*NSEQ+1+kidx))*DIM;
  float s=0;
  for(int j8=0;j8<32;j8++){
    short8 kv = *reinterpret_cast<const short8*>(kr + j8*8);
    #pragma unroll
    for(int u=0;u<8;u++) s += qsh[j8*8+u]*b2f(kv[u]);
  }
  scb[(size_t)b*KG + kidx] = s*0.0625f;
}

// ---------------- pool pass 2: per-b gmax/gsum
__global__ __launch_bounds__(256) void pool_sm(const float* __restrict__ scb,
    float* __restrict__ gms){
  __shared__ float red[4];
  int b=blockIdx.x, t=threadIdx.x;
  float ls[8]; float lmax=-3.4e38f;
  #pragma unroll
  for(int i=0;i<8;i++){
    ls[i] = scb[(size_t)b*KG + t + i*256];
    lmax = fmaxf(lmax, ls[i]);
  }
  float gmax=blockMax256(lmax,red);
  float lsum=0;
  #pragma unroll
  for(int i=0;i<8;i++) lsum += __expf(ls[i]-gmax);
  float gsum=blockSum256(lsum,red);
  if(t==0){ gms[b*2]=gmax; gms[b*2+1]=gsum; }
}

// ---------------- pool pass 3: partial PV (grid 8 x NB)
__global__ __launch_bounds__(256) void pool_pv2(const float* __restrict__ scb,
    const float* __restrict__ gms, const short* __restrict__ vv,
    float* __restrict__ part){
  __shared__ float es[256];
  int kc=blockIdx.x, b=blockIdx.y, t=threadIdx.x;
  float gmax = gms[b*2];
  es[t] = __expf(scb[(size_t)b*KG + kc*256 + t] - gmax);
  __syncthreads();
  float p=0;
  for(int i=0;i<256;i++){
    int kidx = kc*256 + i;
    p += es[i] * b2f(vv[((size_t)(b*NSEQ+1+kidx))*DIM + t]);
  }
  part[((size_t)(b*8)+kc)*DIM + t] = p;
}

// ---------------- pool pass 4: finish (grid NB)
__global__ __launch_bounds__(256) void pool_fin(const float* __restrict__ part,
    const float* __restrict__ gms, float* __restrict__ pooled){
  int b=blockIdx.x, t=threadIdx.x;
  float inv = 1.0f/gms[b*2+1];
  float s=0;
  #pragma unroll
  for(int kc=0;kc<8;kc++) s += part[((size_t)(b*8)+kc)*DIM + t];
  pooled[b*DIM+t] = s*inv;
}

extern "C" void kernel_launch(void* const* d_in, const int* in_sizes, int n_in,
                              void* d_out, int out_size, void* d_ws, size_t ws_size,
                              hipStream_t stream){
  const float* expr   =(const float*)d_in[0];
  const float* coords =(const float*)d_in[1];
  const float* gene_emb=(const float*)d_in[2];
  const float* pos_emb=(const float*)d_in[3];
  const float* val_w  =(const float*)d_in[4];
  const float* val_b  =(const float*)d_in[5];
  const float* val_g  =(const float*)d_in[6];
  const float* val_bb =(const float*)d_in[7];
  const float* sp_w   =(const float*)d_in[8];
  const float* sp_b   =(const float*)d_in[9];
  const float* sp_g   =(const float*)d_in[10];
  const float* sp_bb  =(const float*)d_in[11];
  const float* p_ln1_g=(const float*)d_in[12];
  const float* p_ln1_b=(const float*)d_in[13];
  const float* p_wq   =(const float*)d_in[14];
  const float* p_bq   =(const float*)d_in[15];
  const float* p_wk   =(const float*)d_in[16];
  const float* p_bk   =(const float*)d_in[17];
  const float* p_wv   =(const float*)d_in[18];
  const float* p_bv   =(const float*)d_in[19];
  const float* p_wo   =(const float*)d_in[20];
  const float* p_bo   =(const float*)d_in[21];
  const float* p_ln2_g=(const float*)d_in[22];
  const float* p_ln2_b=(const float*)d_in[23];
  const float* p_ff1_w=(const float*)d_in[24];
  const float* p_ff1_b=(const float*)d_in[25];
  const float* p_ff2_w=(const float*)d_in[26];
  const float* p_ff2_b=(const float*)d_in[27];
  const float* proj   =(const float*)d_in[28];
  const float* q_w    =(const float*)d_in[29];
  const float* q_b    =(const float*)d_in[30];
  const float* k_w    =(const float*)d_in[31];
  const float* k_b    =(const float*)d_in[32];
  const float* v_w    =(const float*)d_in[33];
  const float* v_b    =(const float*)d_in[34];
  const float* o_w    =(const float*)d_in[35];
  const float* o_b    =(const float*)d_in[36];
  float* out = (float*)d_out;

  const size_t BND = (size_t)BN*DIM;     // 16,785,408
  size_t needB = BND*4 + BND*2*4
               + ((size_t)NB*NH*NSEQ + 4 + 2*(size_t)NB*DIM)*4
               + ((size_t)20480 + 2949120 + 1703936)*2;
  if(ws_size < needB){
    hipMemsetAsync(d_out, 0, (size_t)out_size*sizeof(float), stream);
    return;
  }
  float* ws = (float*)d_ws;
  float* x  = ws;                                  // BND fp32
  short* ybf = (short*)(x + BND);
  short* qbf = ybf + BND;
  short* kbf = qbf + BND;
  short* vbf = kbf + BND;
  float* diagk = (float*)(vbf + BND);
  unsigned* kmax = (unsigned*)(diagk + (size_t)NB*NH*NSEQ);
  float* qfin   = (float*)(kmax+4);
  float* pooled = qfin + NB*DIM;
  short* projbf = (short*)(pooled + NB*DIM);       // 320*64
  short* ctxT   = projbf + 20480;                  // 128*80*288
  short* wt     = ctxT + (size_t)128*80*288;       // 1,703,936
  const size_t LW = 786432;
  float* ctxP = (float*)ybf;   // fp32 partials in dead ybf region
  float* scb  = diagk;         // pool scores scratch (65536 floats)
  float* gms  = diagk + 65536; // 64 floats
  float* ppart= gms + 64;      // 65536 floats

  // ---- fused weight prep
  {
    WPArgs a;
    short* wtkk = wt + 2*LW;
    short* wtvv = wtkk + 65536;
    const float* s10[10] = {p_wq, p_wk, p_wv, p_wo,
                            p_wq+(size_t)DIM*DIM, p_wk+(size_t)DIM*DIM,
                            p_wv+(size_t)DIM*DIM, p_wo+(size_t)DIM*DIM,
                            k_w, v_w};
    short* d10[10] = {wt, wt+65536, wt+131072, wt+196608,
                      wt+LW, wt+LW+65536, wt+LW+131072, wt+LW+196608,
                      wtkk, wtvv};
    int ti = 0;
    for(int i=0;i<10;i++){
      a.src[i]=s10[i]; a.dst[i]=d10[i]; a.K[i]=DIM; a.N[i]=DIM;
      a.ts[i]=ti; ti+=64;
    }
    const float* sff[4] = {p_ff1_w, p_ff2_w, p_ff1_w+(size_t)DIM*FFD, p_ff2_w+(size_t)FFD*DIM};
    short* dff[4] = {wt+262144, wt+524288, wt+LW+262144, wt+LW+524288};
    int Kff[4] = {DIM, FFD, DIM, FFD};
    int Nff[4] = {FFD, DIM, FFD, DIM};
    for(int i=0;i<4;i++){
      a.src[10+i]=sff[i]; a.dst[10+i]=dff[i]; a.K[10+i]=Kff[i]; a.N[10+i]=Nff[i];
      a.ts[10+i]=ti; ti+=256;
    }
    a.ts[14]=ti;
    wprep_fused<<<1664,256,0,stream>>>(a);
  }

  // embed + fused LN1(layer 0) -> ybf
  embed_kernel<<<BN/4,256,0,stream>>>(expr,coords,gene_emb,pos_emb,val_w,val_b,val_g,val_bb,
                                      sp_w,sp_b,sp_g,sp_bb, p_ln1_g, p_ln1_b, x, ybf);

  dim3 gdd(2, (BN+127)/128);
  dim3 gqkv(6, (BN+127)/128);
  dim3 gff1(8, (FFROWS2+127)/128);
  dim3 gff2(2, (FFROWS2+127)/128);
  dim3 gkm(7, NB*NH);
  dim3 gkc(8, NB*NH);
  dim3 gcr(80, NB*NH);
  dim3 gq((NSEQ+63)/64, NB*NH);
  dim3 gps(8, NB);
  short* wtkk = wt + 2*LW;
  short* wtvv = wtkk + 65536;

  for(int l=0;l<2;l++){
    short* wl = wt + (size_t)l*LW;
    if(l>0) ln_bf4<<<BN/4,256,0,stream>>>(x, p_ln1_g+l*DIM, p_ln1_b+l*DIM, ybf);
    qkv_gemm<<<gqkv,256,0,stream>>>(ybf, wl, p_bq+l*DIM, p_bk+l*DIM, p_bv+l*DIM,
                                    qbf, kbf, vbf, diagk, BN);
    projprep_kernel<<<80,256,0,stream>>>(proj + (size_t)l*MF*DH, projbf, kmax);
    kside_max<<<gkm,256,0,stream>>>(kbf, projbf, kmax);
    kside_ctx<<<gkc,256,0,stream>>>(kbf, vbf, projbf, diagk, kmax, ctxP);
    ctx_reduce<<<gcr,256,0,stream>>>(ctxP, ctxT);
    qside_mfma<<<gq,256,0,stream>>>(qbf, projbf, ctxT, kbf);   // o -> kbf
    mgemm2<1,0,0><<<gdd,256,0,stream>>>(kbf, wl+196608, p_bo+l*DIM, x, BN, DIM, DIM, nullptr);
    ln_bf4<<<BN/4,256,0,stream>>>(x, p_ln2_g+l*DIM, p_ln2_b+l*DIM, ybf);
    // FF 2-chunk: each chunk's intermediate = FFROWS2 x FFD = qbf+kbf exactly
    for(int c2=0;c2<2;c2++){
      size_t roff=(size_t)c2*FFROWS2;
      mgemm2<2,1,0><<<gff1,256,0,stream>>>(ybf+roff*DIM, wl+262144, p_ff1_b+l*FFD, qbf,
                                           FFROWS2, FFD, DIM, nullptr);
      if(l==1)
        mgemm2<1,0,1><<<gff2,256,0,stream>>>(qbf, wl+524288, p_ff2_b+l*DIM, x+roff*DIM,
                                             FFROWS2, DIM, FFD, ybf+roff*DIM);
      else
        mgemm2<1,0,0><<<gff2,256,0,stream>>>(qbf, wl+524288, p_ff2_b+l*DIM, x+roff*DIM,
                                             FFROWS2, DIM, FFD, nullptr);
    }
  }

  // final pooling attention (ybf already holds bf16(x) via WBF epilogue)
  mgemm2<0,1,0><<<gdd,256,0,stream>>>(ybf, wtkk, k_b, kbf, BN, DIM, DIM, nullptr);
  mgemm2<0,1,0><<<gdd,256,0,stream>>>(ybf, wtvv, v_b, vbf, BN, DIM, DIM, nullptr);
  rowproj_kernel<<<NB,256,0,stream>>>(x, q_w, q_b, qfin, NSEQ*DIM);
  pool_scores<<<gps,256,0,stream>>>(qfin, kbf, scb);
  pool_sm<<<NB,256,0,stream>>>(scb, gms);
  pool_pv2<<<gps,256,0,stream>>>(scb, gms, vbf, ppart);
  pool_fin<<<NB,256,0,stream>>>(ppart, gms, pooled);
  rowproj_kernel<<<NB,256,0,stream>>>(pooled, o_w, o_b, out, DIM);
}